// Round 8
// baseline (1649.174 us; speedup 1.0000x reference)
//
#include <hip/hip_runtime.h>
#include <hip/hip_bf16.h>

#define NN 50000      // nodes
#define NE 800000     // edges
#define NR 500        // relations
#define KEH 256       // input feat dim
#define KRH 128       // proj feat dim
#define NB 98         // node-range bins (node >> 9; 49999>>9 = 97)
#define BSH 9

typedef __attribute__((ext_vector_type(8))) __bf16 bf16x8;
typedef __attribute__((ext_vector_type(4))) float f32x4;

// ---- workspace layout (bytes, 16B aligned), total ~40.6 MiB ----
#define OFF_XH     0UL            // [NN][128] bf16
#define OFF_XT     12800000UL     // [NN][128] bf16
#define OFF_SP     25600000UL     // [NN] float4 (s_hh0,s_hh1,s_th0,s_th1)
#define OFF_DP     26400000UL     // [NN] float4 (s_tt0,s_tt1,s_ht0,s_ht1)
#define OFF_SUMS   27200000UL     // [NR*4] f32 softmax denominators (8000 B)
#define OFF_HS     27208000UL     // [NB] u32 src-bin histogram (512 B)
#define OFF_HD     27208512UL     // [NB] u32 dst-bin histogram (512 B)
// zero region: SUMS..HD = 9024 B = 2256 u32
#define OFF_INVS   27209024UL     // [NR*4] f32 1/(sums+eps) (8000 B)
#define OFF_BASEH  27217024UL     // [NB+1] u32 (512 B)
#define OFF_BASET  27217536UL     // [NB+1] u32 (512 B)
#define OFF_CURH   27218048UL     // [NB] u32 (512 B)
#define OFF_CURT   27218560UL     // [NB] u32 (512 B)
#define OFF_RECH   27219072UL     // [NE] uint2 (node|rel<<16, w1)  6.4 MB
#define OFF_RECT   33619072UL     // [NE] uint2 (node|rel<<16, w2)  6.4 MB
#define OFF_ACC    40019072UL     // [NR][128] f32 accumulator (256,000 B)
#define OFF_AH     40275072UL     // [256] f32 a_h
#define OFF_AT     40276096UL     // [256] f32 a_t
#define OFF_FLAG   40277120UL     // u32: 1 = inputs bf16, 0 = f32
#define OFF_WHH    40277184UL     // [128][256] bf16 w_h hi
#define OFF_WHL    40342720UL     // [128][256] bf16 w_h lo
#define OFF_WTH    40408256UL     // [128][256] bf16 w_t hi
#define OFF_WTL    40473792UL     // [128][256] bf16 w_t lo

__device__ __forceinline__ int clampi(int v, int hi) {  // [0, hi)
    v = v < 0 ? 0 : v;
    return v >= hi ? hi - 1 : v;
}

// block0: sniff input dtype + convert a_h/a_t to f32. blocks 1..: zero
// sums+histograms (2256 u32) and acc (64000 u32).
__global__ __launch_bounds__(256) void k_init(const unsigned* __restrict__ xe_raw,
                                              const void* __restrict__ ah_in, const void* __restrict__ at_in,
                                              unsigned* __restrict__ flag, float* __restrict__ ah32,
                                              float* __restrict__ at32,
                                              unsigned* __restrict__ zero1, unsigned* __restrict__ accz) {
    if (blockIdx.x == 0) {
        __shared__ int votes;
        int t = threadIdx.x;
        if (t == 0) votes = 0;
        __syncthreads();
        if (t < 64) {
            unsigned w = xe_raw[t];
            unsigned ex = (w >> 7) & 0xFFu;
            if (ex >= 115u && ex <= 131u) atomicAdd(&votes, 1);
        }
        __syncthreads();
        int isbf = votes >= 32;
        if (t == 0) flag[0] = (unsigned)isbf;
        if (t < 256) {
            ah32[t] = isbf ? __bfloat162float(((const __hip_bfloat16*)ah_in)[t]) : ((const float*)ah_in)[t];
            at32[t] = isbf ? __bfloat162float(((const __hip_bfloat16*)at_in)[t]) : ((const float*)at_in)[t];
        }
    } else {
        int stride = (gridDim.x - 1) * 256;
        int t0 = (blockIdx.x - 1) * 256 + threadIdx.x;
        for (int i = t0; i < 2256; i += stride) zero1[i] = 0u;
        for (int i = t0; i < NR * KRH; i += stride) accz[i] = 0u;
    }
}

// One-time split of w_h/w_t into bf16 hi/lo (f32 mode) or copy+zero (bf16 mode).
__global__ __launch_bounds__(256) void k_split(const void* __restrict__ wh, const void* __restrict__ wt,
                                               const unsigned* __restrict__ flag,
                                               __bf16* __restrict__ whh, __bf16* __restrict__ whl,
                                               __bf16* __restrict__ wth, __bf16* __restrict__ wtl) {
    int i = blockIdx.x * 256 + threadIdx.x;
    if (i >= KRH * KEH) return;
    if (flag[0]) {
        whh[i] = ((const __bf16*)wh)[i]; whl[i] = (__bf16)0.f;
        wth[i] = ((const __bf16*)wt)[i]; wtl[i] = (__bf16)0.f;
    } else {
        float a = ((const float*)wh)[i];
        float b = ((const float*)wt)[i];
        __bf16 ah_ = (__bf16)a, bh_ = (__bf16)b;
        whh[i] = ah_; whl[i] = (__bf16)(a - (float)ah_);
        wth[i] = bh_; wtl[i] = (__bf16)(b - (float)bh_);
    }
}

// LDS-staged GEMM: block tile 128x128, 4 waves x 32 rows. See round-6 notes.
#define GM 128
#define WROW 40
__global__ __launch_bounds__(256, 2) void k_gemm(const void* __restrict__ xe,
                                                 const unsigned* __restrict__ flag,
                                                 const __bf16* __restrict__ whh, const __bf16* __restrict__ whl,
                                                 const __bf16* __restrict__ wth, const __bf16* __restrict__ wtl,
                                                 __hip_bfloat16* __restrict__ xh, __hip_bfloat16* __restrict__ xt) {
    const int isbf = (int)flag[0];
    __shared__ __bf16 sw[4][128 * WROW];
    int t = threadIdx.x;
    int lane = t & 63, wave = t >> 6;
    int quad = lane >> 4, l16 = lane & 15;
    int rowBase = blockIdx.x * GM + wave * 32;
    int r0 = rowBase + l16, r1 = r0 + 16;
    int ar0 = r0 < NN ? r0 : NN - 1;
    int ar1 = r1 < NN ? r1 : NN - 1;

    f32x4 accH0[8], accH1[8], accT0[8], accT1[8];
    for (int i = 0; i < 8; ++i) {
        accH0[i] = (f32x4){0.f,0.f,0.f,0.f}; accH1[i] = (f32x4){0.f,0.f,0.f,0.f};
        accT0[i] = (f32x4){0.f,0.f,0.f,0.f}; accT1[i] = (f32x4){0.f,0.f,0.f,0.f};
    }
    const int nparts = isbf ? 2 : 4;
    const __bf16* wsrc[4] = {whh, wth, whl, wtl};

    for (int ks = 0; ks < 8; ++ks) {
        int kb = ks * 32;
        __syncthreads();
        for (int part = 0; part < nparts; ++part) {
            const __bf16* wp = wsrc[part];
            for (int half = 0; half < 2; ++half) {
                int idx = half * 256 + t;
                int row = idx >> 2, ko = (idx & 3) * 8;
                uint4 v = *(const uint4*)(wp + (size_t)row * KEH + kb + ko);
                *(uint4*)(&sw[part][row * WROW + ko]) = v;
            }
        }
        __syncthreads();

        bf16x8 a0h, a0l, a1h, a1l;
        if (isbf) {
            a0h = *(const bf16x8*)((const __bf16*)xe + (size_t)ar0 * KEH + kb + quad * 8);
            a1h = *(const bf16x8*)((const __bf16*)xe + (size_t)ar1 * KEH + kb + quad * 8);
        } else {
            const float* p0 = (const float*)xe + (size_t)ar0 * KEH + kb + quad * 8;
            const float* p1 = (const float*)xe + (size_t)ar1 * KEH + kb + quad * 8;
            float4 u0 = *(const float4*)p0, u1 = *(const float4*)(p0 + 4);
            float4 w0 = *(const float4*)p1, w1 = *(const float4*)(p1 + 4);
            float v0[8] = {u0.x,u0.y,u0.z,u0.w,u1.x,u1.y,u1.z,u1.w};
            float v1[8] = {w0.x,w0.y,w0.z,w0.w,w1.x,w1.y,w1.z,w1.w};
            for (int j = 0; j < 8; ++j) {
                __bf16 h0 = (__bf16)v0[j], h1 = (__bf16)v1[j];
                a0h[j] = h0; a0l[j] = (__bf16)(v0[j] - (float)h0);
                a1h[j] = h1; a1l[j] = (__bf16)(v1[j] - (float)h1);
            }
        }
        for (int ct = 0; ct < 8; ++ct) {
            int fo = (ct * 16 + l16) * WROW + quad * 8;
            bf16x8 fh = *(const bf16x8*)(&sw[0][fo]);
            bf16x8 ft = *(const bf16x8*)(&sw[1][fo]);
            accH0[ct] = __builtin_amdgcn_mfma_f32_16x16x32_bf16(a0h, fh, accH0[ct], 0, 0, 0);
            accH1[ct] = __builtin_amdgcn_mfma_f32_16x16x32_bf16(a1h, fh, accH1[ct], 0, 0, 0);
            accT0[ct] = __builtin_amdgcn_mfma_f32_16x16x32_bf16(a0h, ft, accT0[ct], 0, 0, 0);
            accT1[ct] = __builtin_amdgcn_mfma_f32_16x16x32_bf16(a1h, ft, accT1[ct], 0, 0, 0);
            if (!isbf) {
                bf16x8 fhl = *(const bf16x8*)(&sw[2][fo]);
                bf16x8 ftl = *(const bf16x8*)(&sw[3][fo]);
                accH0[ct] = __builtin_amdgcn_mfma_f32_16x16x32_bf16(a0l, fh,  accH0[ct], 0, 0, 0);
                accH0[ct] = __builtin_amdgcn_mfma_f32_16x16x32_bf16(a0h, fhl, accH0[ct], 0, 0, 0);
                accH1[ct] = __builtin_amdgcn_mfma_f32_16x16x32_bf16(a1l, fh,  accH1[ct], 0, 0, 0);
                accH1[ct] = __builtin_amdgcn_mfma_f32_16x16x32_bf16(a1h, fhl, accH1[ct], 0, 0, 0);
                accT0[ct] = __builtin_amdgcn_mfma_f32_16x16x32_bf16(a0l, ft,  accT0[ct], 0, 0, 0);
                accT0[ct] = __builtin_amdgcn_mfma_f32_16x16x32_bf16(a0h, ftl, accT0[ct], 0, 0, 0);
                accT1[ct] = __builtin_amdgcn_mfma_f32_16x16x32_bf16(a1l, ft,  accT1[ct], 0, 0, 0);
                accT1[ct] = __builtin_amdgcn_mfma_f32_16x16x32_bf16(a1h, ftl, accT1[ct], 0, 0, 0);
            }
        }
    }
    for (int ct = 0; ct < 8; ++ct) {
        int col = ct * 16 + l16;
        for (int r2 = 0; r2 < 4; ++r2) {
            int o0 = rowBase + quad * 4 + r2;
            int o1 = o0 + 16;
            if (o0 < NN) {
                xh[(size_t)o0 * KRH + col] = __float2bfloat16(accH0[ct][r2]);
                xt[(size_t)o0 * KRH + col] = __float2bfloat16(accT0[ct][r2]);
            }
            if (o1 < NN) {
                xh[(size_t)o1 * KRH + col] = __float2bfloat16(accH1[ct][r2]);
                xt[(size_t)o1 * KRH + col] = __float2bfloat16(accT1[ct][r2]);
            }
        }
    }
}

// One wave per node: 8 dot products of length 128.
__global__ __launch_bounds__(256) void k_scores(const __hip_bfloat16* __restrict__ xh,
                                                const __hip_bfloat16* __restrict__ xt,
                                                const float* __restrict__ ah, const float* __restrict__ at,
                                                float4* __restrict__ sp, float4* __restrict__ dp) {
    int lane = threadIdx.x & 63;
    int w = threadIdx.x >> 6;
    int n = blockIdx.x * 4 + w;
    if (n >= NN) return;
    float xh0 = __bfloat162float(xh[(size_t)n*KRH + lane]);
    float xh1 = __bfloat162float(xh[(size_t)n*KRH + 64 + lane]);
    float xt0 = __bfloat162float(xt[(size_t)n*KRH + lane]);
    float xt1 = __bfloat162float(xt[(size_t)n*KRH + 64 + lane]);
    float ah00 = ah[lane],       ah01 = ah[64 + lane];
    float ah10 = ah[128 + lane], ah11 = ah[192 + lane];
    float at00 = at[lane],       at01 = at[64 + lane];
    float at10 = at[128 + lane], at11 = at[192 + lane];
    float v[8];
    v[0] = xh0*ah00 + xh1*ah01;
    v[1] = xh0*ah10 + xh1*ah11;
    v[2] = xt0*ah00 + xt1*ah01;
    v[3] = xt0*ah10 + xt1*ah11;
    v[4] = xt0*at00 + xt1*at01;
    v[5] = xt0*at10 + xt1*at11;
    v[6] = xh0*at00 + xh1*at01;
    v[7] = xh0*at10 + xh1*at11;
    for (int off = 32; off; off >>= 1)
        for (int j = 0; j < 8; ++j) v[j] += __shfl_xor(v[j], off);
    if (lane == 0) {
        sp[n] = make_float4(v[0], v[1], v[2], v[3]);
        dp[n] = make_float4(v[4], v[5], v[6], v[7]);
    }
}

__device__ __forceinline__ float eexp(float x) {
    x = x > 0.f ? x : 0.01f * x;
    x = fminf(x, 50.f);
    return __expf(x);
}

// Per edge: 4 exp scores -> LDS segment sums; + src/dst bin histograms.
__global__ __launch_bounds__(256) void k_edge(const int* __restrict__ src, const int* __restrict__ dst,
                                              const int* __restrict__ rel,
                                              const float4* __restrict__ sp, const float4* __restrict__ dp,
                                              float* __restrict__ sums,
                                              unsigned* __restrict__ hs, unsigned* __restrict__ hd) {
    __shared__ float ls[NR * 4];
    __shared__ unsigned lhs[NB], lhd[NB];
    for (int i = threadIdx.x; i < NR * 4; i += 256) ls[i] = 0.f;
    for (int i = threadIdx.x; i < NB; i += 256) { lhs[i] = 0u; lhd[i] = 0u; }
    __syncthreads();
    int stride = gridDim.x * blockDim.x;
    for (int e = blockIdx.x * blockDim.x + threadIdx.x; e < NE; e += stride) {
        int s = clampi(src[e], NN), d = clampi(dst[e], NN), r = clampi(rel[e], NR);
        float4 a = sp[s], b = dp[d];
        atomicAdd(&ls[r*4+0], eexp(a.x + b.x));
        atomicAdd(&ls[r*4+1], eexp(a.y + b.y));
        atomicAdd(&ls[r*4+2], eexp(a.z + b.z));
        atomicAdd(&ls[r*4+3], eexp(a.w + b.w));
        atomicAdd(&lhs[s >> BSH], 1u);
        atomicAdd(&lhd[d >> BSH], 1u);
    }
    __syncthreads();
    for (int i = threadIdx.x; i < NR * 4; i += 256)
        if (ls[i] != 0.f) atomicAdd(&sums[i], ls[i]);
    for (int i = threadIdx.x; i < NB; i += 256) {
        if (lhs[i]) atomicAdd(&hs[i], lhs[i]);
        if (lhd[i]) atomicAdd(&hd[i], lhd[i]);
    }
}

// Scan 98-bin histograms (H and T) -> base/cursor; precompute 1/(sums+eps).
__global__ __launch_bounds__(256) void k_scan(const unsigned* __restrict__ hs, const unsigned* __restrict__ hd,
                                              const float* __restrict__ sums,
                                              unsigned* __restrict__ baseH, unsigned* __restrict__ baseT,
                                              unsigned* __restrict__ curH, unsigned* __restrict__ curT,
                                              float* __restrict__ invs) {
    __shared__ unsigned sc[256];
    int t = threadIdx.x;
    int seg = t >> 7, pos = t & 127;
    unsigned v0 = (pos < NB) ? (seg ? hd[pos] : hs[pos]) : 0u;
    sc[t] = v0;
    __syncthreads();
    for (int off = 1; off < 128; off <<= 1) {
        unsigned add = (pos >= off) ? sc[t - off] : 0u;
        __syncthreads();
        sc[t] += add;
        __syncthreads();
    }
    if (pos < NB) {
        unsigned inc = sc[t];
        unsigned* bp = seg ? baseT : baseH;
        unsigned* cp = seg ? curT : curH;
        bp[pos + 1] = inc;
        cp[pos] = inc - v0;
        if (pos == 0) bp[0] = 0u;
    }
    for (int i = t; i < NR * 4; i += 256) invs[i] = 1.f / (sums[i] + 1e-16f);
}

// Build per-edge records bucketed by src-bin (H) and dst-bin (T):
// rec = (node | rel<<16, w). LDS-staged range reservation per block.
#define SB2 64
__global__ __launch_bounds__(256) void k_mkrec(const int* __restrict__ src, const int* __restrict__ dst,
                                               const int* __restrict__ rel,
                                               const float4* __restrict__ sp, const float4* __restrict__ dp,
                                               const float4* __restrict__ invs4,
                                               unsigned* __restrict__ curH, unsigned* __restrict__ curT,
                                               uint2* __restrict__ recH, uint2* __restrict__ recT) {
    __shared__ unsigned lhH[NB], lhT[NB], lcH[NB], lcT[NB];
    int t = threadIdx.x;
    unsigned lo = blockIdx.x * (NE / SB2);
    unsigned hi = lo + (NE / SB2);
    for (int i = t; i < NB; i += 256) { lhH[i] = 0u; lhT[i] = 0u; }
    __syncthreads();
    for (unsigned e = lo + t; e < hi; e += 256) {
        int s = clampi(src[e], NN), d = clampi(dst[e], NN);
        atomicAdd(&lhH[s >> BSH], 1u);
        atomicAdd(&lhT[d >> BSH], 1u);
    }
    __syncthreads();
    for (int i = t; i < NB; i += 256) {
        lcH[i] = lhH[i] ? atomicAdd(&curH[i], lhH[i]) : 0u;
        lcT[i] = lhT[i] ? atomicAdd(&curT[i], lhT[i]) : 0u;
    }
    __syncthreads();
    for (unsigned e = lo + t; e < hi; e += 256) {
        int s = clampi(src[e], NN), d = clampi(dst[e], NN), r = clampi(rel[e], NR);
        float4 a = sp[s], b = dp[d];
        float4 iv = invs4[r];
        float w1 = eexp(a.x + b.x) * iv.x + eexp(a.y + b.y) * iv.y;
        float w2 = eexp(a.z + b.z) * iv.z + eexp(a.w + b.w) * iv.w;
        unsigned pH = atomicAdd(&lcH[s >> BSH], 1u);
        unsigned pT = atomicAdd(&lcT[d >> BSH], 1u);
        if (pH < NE) recH[pH] = make_uint2((unsigned)s | ((unsigned)r << 16), __float_as_uint(w1));
        if (pT < NE) recT[pT] = make_uint2((unsigned)d | ((unsigned)r << 16), __float_as_uint(w2));
    }
}

// Accumulate: block = (pass, col-group of 32, node-bin). LDS acc over all 500
// rels x 32 cols; gathers confined to a 32-KB slice -> L1/L2-resident.
// 8 slots x 32 lanes; ds_add_f32 accumulation; one global-atomic flush.
__global__ __launch_bounds__(256) void k_accP(const uint2* __restrict__ recH, const uint2* __restrict__ recT,
                                              const unsigned* __restrict__ baseH, const unsigned* __restrict__ baseT,
                                              const __hip_bfloat16* __restrict__ xh,
                                              const __hip_bfloat16* __restrict__ xt,
                                              float* __restrict__ acc) {
    __shared__ float lacc[NR * 32];
    __shared__ uint2 lrec[256];
    int b = blockIdx.x;
    int pass = b / (4 * NB);
    int rem  = b % (4 * NB);
    int g = rem / NB;
    int bin = rem % NB;
    const uint2* rec = pass ? recT : recH;
    const unsigned* base = pass ? baseT : baseH;
    const unsigned short* xs = (const unsigned short*)(pass ? xt : xh);
    unsigned b0 = base[bin];
    unsigned cnt = base[bin + 1] - b0;
    if (cnt > NE) cnt = 0;            // poison guard
    int t = threadIdx.x;
    int slot = t >> 5, c = t & 31;
    for (int i = t; i < NR * 32; i += 256) lacc[i] = 0.f;
    __syncthreads();
    for (unsigned cb = 0; cb < cnt; cb += 256u) {
        unsigned cn = cnt - cb; if (cn > 256u) cn = 256u;
        if ((unsigned)t < cn) lrec[t] = rec[b0 + cb + t];
        __syncthreads();
        for (unsigned j = (unsigned)slot; j < cn; j += 8) {
            uint2 rr = lrec[j];
            unsigned node = rr.x & 0xFFFFu;
            unsigned rl = rr.x >> 16;
            float w = __uint_as_float(rr.y);
            unsigned short u = xs[(size_t)node * KRH + g * 32 + c];
            float x = __uint_as_float((unsigned)u << 16);
            atomicAdd(&lacc[rl * 32 + c], w * x);
        }
        __syncthreads();
    }
    for (int i = t; i < NR * 32; i += 256) {
        float v = lacc[i];
        if (v != 0.f) atomicAdd(&acc[(size_t)(i >> 5) * KRH + g * 32 + (i & 31)], v);
    }
}

// Output dtype follows input dtype (reference returns x_e.dtype).
__global__ __launch_bounds__(256) void k_out(const float* __restrict__ acc,
                                             const unsigned* __restrict__ flag, void* __restrict__ out) {
    int i = blockIdx.x * 256 + threadIdx.x;
    if (i < NR * KRH) {
        float v = acc[i] * 0.25f;     // / num_heads(2) / 2
        if (!isfinite(v)) v = 0.f;
        if (flag[0]) ((__hip_bfloat16*)out)[i] = __float2bfloat16(v);
        else         ((float*)out)[i] = v;
    }
}

extern "C" void kernel_launch(void* const* d_in, const int* in_sizes, int n_in,
                              void* d_out, int out_size, void* d_ws, size_t ws_size,
                              hipStream_t stream) {
    const void* xe  = d_in[0];
    const int* eidx = (const int*)d_in[1];
    const int* rel  = (const int*)d_in[2];
    const void* wh  = d_in[3];
    const void* wt  = d_in[4];
    const void* ahp = d_in[5];
    const void* atp = d_in[6];

    const int* src = eidx;
    const int* dst = eidx + NE;

    char* ws = (char*)d_ws;
    __hip_bfloat16* xh = (__hip_bfloat16*)(ws + OFF_XH);
    __hip_bfloat16* xt = (__hip_bfloat16*)(ws + OFF_XT);
    float4*   sp     = (float4*)(ws + OFF_SP);
    float4*   dp     = (float4*)(ws + OFF_DP);
    float*    sums   = (float*)(ws + OFF_SUMS);
    unsigned* hs     = (unsigned*)(ws + OFF_HS);
    unsigned* hd     = (unsigned*)(ws + OFF_HD);
    float*    invs   = (float*)(ws + OFF_INVS);
    unsigned* baseH  = (unsigned*)(ws + OFF_BASEH);
    unsigned* baseT  = (unsigned*)(ws + OFF_BASET);
    unsigned* curH   = (unsigned*)(ws + OFF_CURH);
    unsigned* curT   = (unsigned*)(ws + OFF_CURT);
    uint2*    recH   = (uint2*)(ws + OFF_RECH);
    uint2*    recT   = (uint2*)(ws + OFF_RECT);
    float*    acc    = (float*)(ws + OFF_ACC);
    float*    ah32   = (float*)(ws + OFF_AH);
    float*    at32   = (float*)(ws + OFF_AT);
    unsigned* flag   = (unsigned*)(ws + OFF_FLAG);
    __bf16*   whh    = (__bf16*)(ws + OFF_WHH);
    __bf16*   whl    = (__bf16*)(ws + OFF_WHL);
    __bf16*   wth    = (__bf16*)(ws + OFF_WTH);
    __bf16*   wtl    = (__bf16*)(ws + OFF_WTL);

    k_init<<<261, 256, 0, stream>>>((const unsigned*)xe, ahp, atp, flag, ah32, at32,
                                     (unsigned*)(ws + OFF_SUMS), (unsigned*)acc);
    k_split<<<(KRH * KEH + 255) / 256, 256, 0, stream>>>(wh, wt, flag, whh, whl, wth, wtl);
    k_gemm<<<(NN + GM - 1) / GM, 256, 0, stream>>>(xe, flag, whh, whl, wth, wtl, xh, xt);
    k_scores<<<(NN + 3) / 4, 256, 0, stream>>>(xh, xt, ah32, at32, sp, dp);
    k_edge<<<512, 256, 0, stream>>>(src, dst, rel, sp, dp, sums, hs, hd);
    k_scan<<<1, 256, 0, stream>>>(hs, hd, sums, baseH, baseT, curH, curT, invs);
    k_mkrec<<<SB2, 256, 0, stream>>>(src, dst, rel, sp, dp, (const float4*)invs, curH, curT, recH, recT);
    k_accP<<<2 * 4 * NB, 256, 0, stream>>>(recH, recT, baseH, baseT, xh, xt, acc);
    k_out<<<(NR * KRH + 255) / 256, 256, 0, stream>>>(acc, flag, d_out);
}

// Round 9
// 415.631 us; speedup vs baseline: 3.9679x; 3.9679x over previous
//
#include <hip/hip_runtime.h>
#include <hip/hip_bf16.h>

#define NN 50000      // nodes
#define NE 800000     // edges
#define NR 500        // relations
#define KEH 256       // input feat dim
#define KRH 128       // proj feat dim
#define NSB 8         // node super-bins (node / 6250), aligned to 8 XCDs
#define SBW 6250      // super-bin width
#define NBK (NR*NSB)  // 4000 buckets

typedef __attribute__((ext_vector_type(8))) __bf16 bf16x8;
typedef __attribute__((ext_vector_type(4))) float f32x4;

// ---- workspace layout (bytes, 16B aligned), total ~40.5 MiB ----
#define OFF_XH     0UL            // [NN][128] bf16
#define OFF_XT     12800000UL     // [NN][128] bf16
#define OFF_SP     25600000UL     // [NN] float4
#define OFF_DP     26400000UL     // [NN] float4
#define OFF_SUMS   27200000UL     // [NR*4] f32 (8000 B)
#define OFF_HISTH  27208000UL     // [NBK] u32 (16000 B)
#define OFF_HISTT  27224000UL     // [NBK] u32 (16000 B)
// zero region SUMS..HISTT = 40000 B = 10000 u32
#define OFF_INVS   27240000UL     // [NR*4] f32
#define OFF_BASEH  27248000UL     // [NBK+1] u32 (pad to 16016)
#define OFF_BASET  27264016UL     // [NBK+1] u32
#define OFF_CURH   27280032UL     // [NBK] u32
#define OFF_CURT   27296032UL     // [NBK] u32
#define OFF_RECH   27312032UL     // [NE] uint2 (node, w1) 6.4 MB
#define OFF_RECT   33712032UL     // [NE] uint2 (node, w2) 6.4 MB
#define OFF_PART   40112032UL     // [NBK][128] f32 partials (2.048 MB)
#define OFF_AH     42160032UL     // [256] f32
#define OFF_AT     42161056UL     // [256] f32
#define OFF_FLAG   42162080UL     // u32
#define OFF_WHH    42162144UL     // [128][256] bf16
#define OFF_WHL    42227680UL
#define OFF_WTH    42293216UL
#define OFF_WTL    42358752UL     // end 42424288

__device__ __forceinline__ int clampi(int v, int hi) {  // [0, hi)
    v = v < 0 ? 0 : v;
    return v >= hi ? hi - 1 : v;
}

// Wave-replicated dtype sniff: every wave inspects the same 64 words of x_e.
// Low u16 of an f32 word is uniform mantissa bits (~6% in-window); if inputs
// are bf16 pairs it's an N(0,1) bf16 (exp ~127, ~100% in-window).
__device__ __forceinline__ int sniff_isbf(const unsigned* xe_raw) {
    int lane = threadIdx.x & 63;
    unsigned w = xe_raw[lane];
    unsigned ex = (w >> 7) & 0xFFu;
    bool hit = (ex >= 115u && ex <= 131u);
    return __popcll(__ballot(hit)) >= 32;
}

// block 0: flag + a_h/a_t convert. blocks 1..128: weight split. blocks 129+:
// zero sums + histH + histT (10000 u32).
__global__ __launch_bounds__(256) void k_init(const unsigned* __restrict__ xe_raw,
                                              const void* __restrict__ ah_in, const void* __restrict__ at_in,
                                              const void* __restrict__ wh, const void* __restrict__ wt,
                                              unsigned* __restrict__ flag, float* __restrict__ ah32,
                                              float* __restrict__ at32,
                                              __bf16* __restrict__ whh, __bf16* __restrict__ whl,
                                              __bf16* __restrict__ wth, __bf16* __restrict__ wtl,
                                              unsigned* __restrict__ zero1) {
    int isbf = sniff_isbf(xe_raw);
    int t = threadIdx.x;
    if (blockIdx.x == 0) {
        if (t == 0) flag[0] = (unsigned)isbf;
        ah32[t] = isbf ? __bfloat162float(((const __hip_bfloat16*)ah_in)[t]) : ((const float*)ah_in)[t];
        at32[t] = isbf ? __bfloat162float(((const __hip_bfloat16*)at_in)[t]) : ((const float*)at_in)[t];
    } else if (blockIdx.x <= 128) {
        int i = (blockIdx.x - 1) * 256 + t;   // [0, 32768)
        if (isbf) {
            whh[i] = ((const __bf16*)wh)[i]; whl[i] = (__bf16)0.f;
            wth[i] = ((const __bf16*)wt)[i]; wtl[i] = (__bf16)0.f;
        } else {
            float a = ((const float*)wh)[i];
            float b = ((const float*)wt)[i];
            __bf16 ah_ = (__bf16)a, bh_ = (__bf16)b;
            whh[i] = ah_; whl[i] = (__bf16)(a - (float)ah_);
            wth[i] = bh_; wtl[i] = (__bf16)(b - (float)bh_);
        }
    } else {
        int stride = (gridDim.x - 129) * 256;
        for (int i = (blockIdx.x - 129) * 256 + t; i < 10000; i += stride) zero1[i] = 0u;
    }
}

// LDS-staged GEMM: block tile 128x128, 4 waves x 32 rows (round-6 notes).
#define GM 128
#define WROW 40
__global__ __launch_bounds__(256, 2) void k_gemm(const void* __restrict__ xe,
                                                 const unsigned* __restrict__ flag,
                                                 const __bf16* __restrict__ whh, const __bf16* __restrict__ whl,
                                                 const __bf16* __restrict__ wth, const __bf16* __restrict__ wtl,
                                                 __hip_bfloat16* __restrict__ xh, __hip_bfloat16* __restrict__ xt) {
    const int isbf = (int)flag[0];
    __shared__ __bf16 sw[4][128 * WROW];
    int t = threadIdx.x;
    int lane = t & 63, wave = t >> 6;
    int quad = lane >> 4, l16 = lane & 15;
    int rowBase = blockIdx.x * GM + wave * 32;
    int r0 = rowBase + l16, r1 = r0 + 16;
    int ar0 = r0 < NN ? r0 : NN - 1;
    int ar1 = r1 < NN ? r1 : NN - 1;

    f32x4 accH0[8], accH1[8], accT0[8], accT1[8];
    for (int i = 0; i < 8; ++i) {
        accH0[i] = (f32x4){0.f,0.f,0.f,0.f}; accH1[i] = (f32x4){0.f,0.f,0.f,0.f};
        accT0[i] = (f32x4){0.f,0.f,0.f,0.f}; accT1[i] = (f32x4){0.f,0.f,0.f,0.f};
    }
    const int nparts = isbf ? 2 : 4;
    const __bf16* wsrc[4] = {whh, wth, whl, wtl};

    for (int ks = 0; ks < 8; ++ks) {
        int kb = ks * 32;
        __syncthreads();
        for (int part = 0; part < nparts; ++part) {
            const __bf16* wp = wsrc[part];
            for (int half = 0; half < 2; ++half) {
                int idx = half * 256 + t;
                int row = idx >> 2, ko = (idx & 3) * 8;
                uint4 v = *(const uint4*)(wp + (size_t)row * KEH + kb + ko);
                *(uint4*)(&sw[part][row * WROW + ko]) = v;
            }
        }
        __syncthreads();

        bf16x8 a0h, a0l, a1h, a1l;
        if (isbf) {
            a0h = *(const bf16x8*)((const __bf16*)xe + (size_t)ar0 * KEH + kb + quad * 8);
            a1h = *(const bf16x8*)((const __bf16*)xe + (size_t)ar1 * KEH + kb + quad * 8);
        } else {
            const float* p0 = (const float*)xe + (size_t)ar0 * KEH + kb + quad * 8;
            const float* p1 = (const float*)xe + (size_t)ar1 * KEH + kb + quad * 8;
            float4 u0 = *(const float4*)p0, u1 = *(const float4*)(p0 + 4);
            float4 w0 = *(const float4*)p1, w1 = *(const float4*)(p1 + 4);
            float v0[8] = {u0.x,u0.y,u0.z,u0.w,u1.x,u1.y,u1.z,u1.w};
            float v1[8] = {w0.x,w0.y,w0.z,w0.w,w1.x,w1.y,w1.z,w1.w};
            for (int j = 0; j < 8; ++j) {
                __bf16 h0 = (__bf16)v0[j], h1 = (__bf16)v1[j];
                a0h[j] = h0; a0l[j] = (__bf16)(v0[j] - (float)h0);
                a1h[j] = h1; a1l[j] = (__bf16)(v1[j] - (float)h1);
            }
        }
        for (int ct = 0; ct < 8; ++ct) {
            int fo = (ct * 16 + l16) * WROW + quad * 8;
            bf16x8 fh = *(const bf16x8*)(&sw[0][fo]);
            bf16x8 ft = *(const bf16x8*)(&sw[1][fo]);
            accH0[ct] = __builtin_amdgcn_mfma_f32_16x16x32_bf16(a0h, fh, accH0[ct], 0, 0, 0);
            accH1[ct] = __builtin_amdgcn_mfma_f32_16x16x32_bf16(a1h, fh, accH1[ct], 0, 0, 0);
            accT0[ct] = __builtin_amdgcn_mfma_f32_16x16x32_bf16(a0h, ft, accT0[ct], 0, 0, 0);
            accT1[ct] = __builtin_amdgcn_mfma_f32_16x16x32_bf16(a1h, ft, accT1[ct], 0, 0, 0);
            if (!isbf) {
                bf16x8 fhl = *(const bf16x8*)(&sw[2][fo]);
                bf16x8 ftl = *(const bf16x8*)(&sw[3][fo]);
                accH0[ct] = __builtin_amdgcn_mfma_f32_16x16x32_bf16(a0l, fh,  accH0[ct], 0, 0, 0);
                accH0[ct] = __builtin_amdgcn_mfma_f32_16x16x32_bf16(a0h, fhl, accH0[ct], 0, 0, 0);
                accH1[ct] = __builtin_amdgcn_mfma_f32_16x16x32_bf16(a1l, fh,  accH1[ct], 0, 0, 0);
                accH1[ct] = __builtin_amdgcn_mfma_f32_16x16x32_bf16(a1h, fhl, accH1[ct], 0, 0, 0);
                accT0[ct] = __builtin_amdgcn_mfma_f32_16x16x32_bf16(a0l, ft,  accT0[ct], 0, 0, 0);
                accT0[ct] = __builtin_amdgcn_mfma_f32_16x16x32_bf16(a0h, ftl, accT0[ct], 0, 0, 0);
                accT1[ct] = __builtin_amdgcn_mfma_f32_16x16x32_bf16(a1l, ft,  accT1[ct], 0, 0, 0);
                accT1[ct] = __builtin_amdgcn_mfma_f32_16x16x32_bf16(a1h, ftl, accT1[ct], 0, 0, 0);
            }
        }
    }
    for (int ct = 0; ct < 8; ++ct) {
        int col = ct * 16 + l16;
        for (int r2 = 0; r2 < 4; ++r2) {
            int o0 = rowBase + quad * 4 + r2;
            int o1 = o0 + 16;
            if (o0 < NN) {
                xh[(size_t)o0 * KRH + col] = __float2bfloat16(accH0[ct][r2]);
                xt[(size_t)o0 * KRH + col] = __float2bfloat16(accT0[ct][r2]);
            }
            if (o1 < NN) {
                xh[(size_t)o1 * KRH + col] = __float2bfloat16(accH1[ct][r2]);
                xt[(size_t)o1 * KRH + col] = __float2bfloat16(accT1[ct][r2]);
            }
        }
    }
}

// One wave per node: 8 dot products of length 128.
__global__ __launch_bounds__(256) void k_scores(const __hip_bfloat16* __restrict__ xh,
                                                const __hip_bfloat16* __restrict__ xt,
                                                const float* __restrict__ ah, const float* __restrict__ at,
                                                float4* __restrict__ sp, float4* __restrict__ dp) {
    int lane = threadIdx.x & 63;
    int w = threadIdx.x >> 6;
    int n = blockIdx.x * 4 + w;
    if (n >= NN) return;
    float xh0 = __bfloat162float(xh[(size_t)n*KRH + lane]);
    float xh1 = __bfloat162float(xh[(size_t)n*KRH + 64 + lane]);
    float xt0 = __bfloat162float(xt[(size_t)n*KRH + lane]);
    float xt1 = __bfloat162float(xt[(size_t)n*KRH + 64 + lane]);
    float ah00 = ah[lane],       ah01 = ah[64 + lane];
    float ah10 = ah[128 + lane], ah11 = ah[192 + lane];
    float at00 = at[lane],       at01 = at[64 + lane];
    float at10 = at[128 + lane], at11 = at[192 + lane];
    float v[8];
    v[0] = xh0*ah00 + xh1*ah01;
    v[1] = xh0*ah10 + xh1*ah11;
    v[2] = xt0*ah00 + xt1*ah01;
    v[3] = xt0*ah10 + xt1*ah11;
    v[4] = xt0*at00 + xt1*at01;
    v[5] = xt0*at10 + xt1*at11;
    v[6] = xh0*at00 + xh1*at01;
    v[7] = xh0*at10 + xh1*at11;
    for (int off = 32; off; off >>= 1)
        for (int j = 0; j < 8; ++j) v[j] += __shfl_xor(v[j], off);
    if (lane == 0) {
        sp[n] = make_float4(v[0], v[1], v[2], v[3]);
        dp[n] = make_float4(v[4], v[5], v[6], v[7]);
    }
}

__device__ __forceinline__ float eexp(float x) {
    x = x > 0.f ? x : 0.01f * x;
    x = fminf(x, 50.f);
    return __expf(x);
}

// Per edge: 4 exp scores -> LDS segment sums + (rel,sbin) histograms (H by
// src-sbin, T by dst-sbin). 256 blocks.
__global__ __launch_bounds__(256) void k_edge(const int* __restrict__ src, const int* __restrict__ dst,
                                              const int* __restrict__ rel,
                                              const float4* __restrict__ sp, const float4* __restrict__ dp,
                                              float* __restrict__ sums,
                                              unsigned* __restrict__ histH, unsigned* __restrict__ histT) {
    __shared__ float ls[NR * 4];
    __shared__ unsigned lhH[NBK], lhT[NBK];
    for (int i = threadIdx.x; i < NR * 4; i += 256) ls[i] = 0.f;
    for (int i = threadIdx.x; i < NBK; i += 256) { lhH[i] = 0u; lhT[i] = 0u; }
    __syncthreads();
    int stride = gridDim.x * blockDim.x;
    for (int e = blockIdx.x * blockDim.x + threadIdx.x; e < NE; e += stride) {
        int s = clampi(src[e], NN), d = clampi(dst[e], NN), r = clampi(rel[e], NR);
        float4 a = sp[s], b = dp[d];
        atomicAdd(&ls[r*4+0], eexp(a.x + b.x));
        atomicAdd(&ls[r*4+1], eexp(a.y + b.y));
        atomicAdd(&ls[r*4+2], eexp(a.z + b.z));
        atomicAdd(&ls[r*4+3], eexp(a.w + b.w));
        atomicAdd(&lhH[r * NSB + s / SBW], 1u);
        atomicAdd(&lhT[r * NSB + d / SBW], 1u);
    }
    __syncthreads();
    for (int i = threadIdx.x; i < NR * 4; i += 256)
        if (ls[i] != 0.f) atomicAdd(&sums[i], ls[i]);
    for (int i = threadIdx.x; i < NBK; i += 256) {
        if (lhH[i]) atomicAdd(&histH[i], lhH[i]);
        if (lhT[i]) atomicAdd(&histT[i], lhT[i]);
    }
}

// Scan both 4000-bin histograms -> base/cursor; invs = 1/(sums+eps).
__global__ __launch_bounds__(1024) void k_scan2(const unsigned* __restrict__ histH,
                                                const unsigned* __restrict__ histT,
                                                const float* __restrict__ sums,
                                                unsigned* __restrict__ baseH, unsigned* __restrict__ baseT,
                                                unsigned* __restrict__ curH, unsigned* __restrict__ curT,
                                                float* __restrict__ invs) {
    __shared__ unsigned sc[1024];
    int t = threadIdx.x;
    for (int pass = 0; pass < 2; ++pass) {
        const unsigned* h = pass ? histT : histH;
        unsigned* base = pass ? baseT : baseH;
        unsigned* cur  = pass ? curT  : curH;
        int j0 = t * 4;
        unsigned v[4], s = 0;
        for (int k = 0; k < 4; ++k) { v[k] = (j0 + k < NBK) ? h[j0 + k] : 0u; s += v[k]; }
        sc[t] = s;
        __syncthreads();
        for (int off = 1; off < 1024; off <<= 1) {
            unsigned add = (t >= off) ? sc[t - off] : 0u;
            __syncthreads();
            sc[t] += add;
            __syncthreads();
        }
        unsigned run = sc[t] - s;   // exclusive prefix
        for (int k = 0; k < 4; ++k) {
            if (j0 + k < NBK) { base[j0 + k] = run; cur[j0 + k] = run; run += v[k]; }
        }
        if (t == 1023) base[NBK] = sc[1023];
        __syncthreads();
    }
    for (int i = t; i < NR * 4; i += 1024) invs[i] = 1.f / (sums[i] + 1e-16f);
}

// Build weighted records bucketed by (rel, sbin): recH = (src, w1) by src-sbin,
// recT = (dst, w2) by dst-sbin. 64 blocks; in-place LDS hist->cursor.
#define MB 64
__global__ __launch_bounds__(256) void k_mkrec(const int* __restrict__ src, const int* __restrict__ dst,
                                               const int* __restrict__ rel,
                                               const float4* __restrict__ sp, const float4* __restrict__ dp,
                                               const float4* __restrict__ invs4,
                                               unsigned* __restrict__ curH, unsigned* __restrict__ curT,
                                               uint2* __restrict__ recH, uint2* __restrict__ recT) {
    __shared__ unsigned lhH[NBK], lhT[NBK];
    int t = threadIdx.x;
    unsigned lo = blockIdx.x * (NE / MB);
    unsigned hi = lo + (NE / MB);
    for (int i = t; i < NBK; i += 256) { lhH[i] = 0u; lhT[i] = 0u; }
    __syncthreads();
    for (unsigned e = lo + t; e < hi; e += 256) {
        int s = clampi(src[e], NN), d = clampi(dst[e], NN), r = clampi(rel[e], NR);
        atomicAdd(&lhH[r * NSB + s / SBW], 1u);
        atomicAdd(&lhT[r * NSB + d / SBW], 1u);
    }
    __syncthreads();
    for (int i = t; i < NBK; i += 256) {   // in-place: count -> start cursor
        unsigned c = lhH[i];
        lhH[i] = c ? atomicAdd(&curH[i], c) : 0u;
        c = lhT[i];
        lhT[i] = c ? atomicAdd(&curT[i], c) : 0u;
    }
    __syncthreads();
    for (unsigned e = lo + t; e < hi; e += 256) {
        int s = clampi(src[e], NN), d = clampi(dst[e], NN), r = clampi(rel[e], NR);
        float4 a = sp[s], b = dp[d];
        float4 iv = invs4[r];
        float w1 = eexp(a.x + b.x) * iv.x + eexp(a.y + b.y) * iv.y;
        float w2 = eexp(a.z + b.z) * iv.z + eexp(a.w + b.w) * iv.w;
        unsigned pH = atomicAdd(&lhH[r * NSB + s / SBW], 1u);
        unsigned pT = atomicAdd(&lhT[r * NSB + d / SBW], 1u);
        if (pH < NE) recH[pH] = make_uint2((unsigned)s, __float_as_uint(w1));
        if (pT < NE) recT[pT] = make_uint2((unsigned)d, __float_as_uint(w2));
    }
}

// One block per (rel,sbin) bucket: blockIdx = rel*8 + sbin, so sbin tracks the
// XCD round-robin and each block's 2x1.6MB gather window stays L2-local.
// Register accumulation; direct wave-uniform rec loads; non-atomic part store.
__global__ __launch_bounds__(256) void k_accR(const uint2* __restrict__ recH, const uint2* __restrict__ recT,
                                              const unsigned* __restrict__ baseH, const unsigned* __restrict__ baseT,
                                              const __hip_bfloat16* __restrict__ xh,
                                              const __hip_bfloat16* __restrict__ xt,
                                              float* __restrict__ part) {
    __shared__ float red[4][128];
    int b = blockIdx.x;
    int t = threadIdx.x, lane = t & 63, wv = t >> 6;
    int c2 = lane * 2;
    float ax = 0.f, ay = 0.f;
    for (int pass = 0; pass < 2; ++pass) {
        const uint2* rec = pass ? recT : recH;
        const unsigned* base = pass ? baseT : baseH;
        const unsigned short* xs = (const unsigned short*)(pass ? xt : xh);
        unsigned b0 = base[b];
        unsigned cnt = base[b + 1] - b0;
        if (cnt > NE) cnt = 0;        // poison guard
        for (unsigned j = (unsigned)wv; j < cnt; j += 4) {
            uint2 rr = rec[b0 + j];   // wave-uniform address -> broadcast
            unsigned node = rr.x;
            if (node >= NN) node = 0;
            float w = __uint_as_float(rr.y);
            unsigned u = *(const unsigned*)(xs + (size_t)node * KRH + c2);
            ax = fmaf(w, __uint_as_float(u << 16), ax);
            ay = fmaf(w, __uint_as_float(u & 0xffff0000u), ay);
        }
    }
    red[wv][c2] = ax; red[wv][c2 + 1] = ay;
    __syncthreads();
    if (wv == 0) {
        float vx = red[0][c2] + red[1][c2] + red[2][c2] + red[3][c2];
        float vy = red[0][c2+1] + red[1][c2+1] + red[2][c2+1] + red[3][c2+1];
        *(float2*)(&part[(size_t)b * KRH + c2]) = make_float2(vx, vy);
    }
}

// out[r][c] = 0.25 * sum_sbin part[r*8+sbin][c]; dtype follows input.
__global__ __launch_bounds__(256) void k_out(const float* __restrict__ part,
                                             const unsigned* __restrict__ flag, void* __restrict__ out) {
    int i = blockIdx.x * 256 + threadIdx.x;
    if (i < NR * KRH) {
        int r = i >> 7, c = i & 127;
        float v = 0.f;
        for (int s = 0; s < NSB; ++s) v += part[(size_t)(r * NSB + s) * KRH + c];
        v *= 0.25f;                   // / num_heads(2) / 2
        if (!isfinite(v)) v = 0.f;
        if (flag[0]) ((__hip_bfloat16*)out)[i] = __float2bfloat16(v);
        else         ((float*)out)[i] = v;
    }
}

extern "C" void kernel_launch(void* const* d_in, const int* in_sizes, int n_in,
                              void* d_out, int out_size, void* d_ws, size_t ws_size,
                              hipStream_t stream) {
    const void* xe  = d_in[0];
    const int* eidx = (const int*)d_in[1];
    const int* rel  = (const int*)d_in[2];
    const void* wh  = d_in[3];
    const void* wt  = d_in[4];
    const void* ahp = d_in[5];
    const void* atp = d_in[6];

    const int* src = eidx;
    const int* dst = eidx + NE;

    char* ws = (char*)d_ws;
    __hip_bfloat16* xh = (__hip_bfloat16*)(ws + OFF_XH);
    __hip_bfloat16* xt = (__hip_bfloat16*)(ws + OFF_XT);
    float4*   sp     = (float4*)(ws + OFF_SP);
    float4*   dp     = (float4*)(ws + OFF_DP);
    float*    sums   = (float*)(ws + OFF_SUMS);
    unsigned* histH  = (unsigned*)(ws + OFF_HISTH);
    unsigned* histT  = (unsigned*)(ws + OFF_HISTT);
    float*    invs   = (float*)(ws + OFF_INVS);
    unsigned* baseH  = (unsigned*)(ws + OFF_BASEH);
    unsigned* baseT  = (unsigned*)(ws + OFF_BASET);
    unsigned* curH   = (unsigned*)(ws + OFF_CURH);
    unsigned* curT   = (unsigned*)(ws + OFF_CURT);
    uint2*    recH   = (uint2*)(ws + OFF_RECH);
    uint2*    recT   = (uint2*)(ws + OFF_RECT);
    float*    partp  = (float*)(ws + OFF_PART);
    float*    ah32   = (float*)(ws + OFF_AH);
    float*    at32   = (float*)(ws + OFF_AT);
    unsigned* flag   = (unsigned*)(ws + OFF_FLAG);
    __bf16*   whh    = (__bf16*)(ws + OFF_WHH);
    __bf16*   whl    = (__bf16*)(ws + OFF_WHL);
    __bf16*   wth    = (__bf16*)(ws + OFF_WTH);
    __bf16*   wtl    = (__bf16*)(ws + OFF_WTL);

    k_init<<<161, 256, 0, stream>>>((const unsigned*)xe, ahp, atp, wh, wt, flag, ah32, at32,
                                     whh, whl, wth, wtl, (unsigned*)(ws + OFF_SUMS));
    k_gemm<<<(NN + GM - 1) / GM, 256, 0, stream>>>(xe, flag, whh, whl, wth, wtl, xh, xt);
    k_scores<<<(NN + 3) / 4, 256, 0, stream>>>(xh, xt, ah32, at32, sp, dp);
    k_edge<<<256, 256, 0, stream>>>(src, dst, rel, sp, dp, sums, histH, histT);
    k_scan2<<<1, 1024, 0, stream>>>(histH, histT, sums, baseH, baseT, curH, curT, invs);
    k_mkrec<<<MB, 256, 0, stream>>>(src, dst, rel, sp, dp, (const float4*)invs, curH, curT, recH, recT);
    k_accR<<<NBK, 256, 0, stream>>>(recH, recT, baseH, baseT, xh, xt, partp);
    k_out<<<(NR * KRH + 255) / 256, 256, 0, stream>>>(partp, flag, d_out);
}

// Round 10
// 369.582 us; speedup vs baseline: 4.4623x; 1.1246x over previous
//
#include <hip/hip_runtime.h>
#include <hip/hip_bf16.h>

#define NN 50000      // nodes
#define NE 800000     // edges
#define NR 500        // relations
#define KEH 256       // input feat dim
#define KRH 128       // proj feat dim
#define NSB 8         // node super-bins (node / 6250), aligned to 8 XCDs
#define SBW 6250      // super-bin width
#define NBK (NR*NSB)  // 4000 buckets
#define NBE 256       // edge-pass blocks (k_edge / k_mkrec)
#define EPB (NE/NBE)  // 3125 edges per block

typedef __attribute__((ext_vector_type(8))) __bf16 bf16x8;
typedef __attribute__((ext_vector_type(4))) float f32x4;

// ---- workspace layout (bytes, 16B aligned), total ~50.6 MiB ----
#define OFF_XH     0UL            // [NN][128] bf16
#define OFF_XT     12800000UL     // [NN][128] bf16
#define OFF_SP     25600000UL     // [NN] float4
#define OFF_DP     26400000UL     // [NN] float4
#define OFF_SUMS   27200000UL     // [NR*4] f32 (8000 B)
#define OFF_HISTH  27208000UL     // [NBK] u32 totals (16000 B)
#define OFF_HISTT  27224000UL     // [NBK] u32 totals (16000 B)
// zero region SUMS..HISTT = 40000 B = 10000 u32
#define OFF_INVS   27240000UL     // [NR*4] f32
#define OFF_BASEH  27248000UL     // [NBK+1] u32 (16016 B)
#define OFF_BASET  27264016UL     // [NBK+1] u32
#define OFF_RECH   27312032UL     // [NE] uint2 (node, w1) 6.4 MB
#define OFF_RECT   33712032UL     // [NE] uint2 (node, w2) 6.4 MB
#define OFF_PART   40112032UL     // [NBK][128] f32 partials (2.048 MB)
#define OFF_AH     42160032UL     // [256] f32
#define OFF_AT     42161056UL     // [256] f32
#define OFF_FLAG   42162080UL     // u32
#define OFF_WHH    42162144UL     // [128][256] bf16
#define OFF_WHL    42227680UL
#define OFF_WTH    42293216UL
#define OFF_WTL    42358752UL
#define OFF_HPBH   42424288UL     // [NBE][NBK] u32 per-block hist/offsets 4.096 MB
#define OFF_HPBT   46520288UL     // [NBE][NBK] u32                       4.096 MB
// end 50,616,288

__device__ __forceinline__ int clampi(int v, int hi) {  // [0, hi)
    v = v < 0 ? 0 : v;
    return v >= hi ? hi - 1 : v;
}

// Wave-replicated dtype sniff (see round-8 notes).
__device__ __forceinline__ int sniff_isbf(const unsigned* xe_raw) {
    int lane = threadIdx.x & 63;
    unsigned w = xe_raw[lane];
    unsigned ex = (w >> 7) & 0xFFu;
    bool hit = (ex >= 115u && ex <= 131u);
    return __popcll(__ballot(hit)) >= 32;
}

// block 0: flag + a_h/a_t convert. blocks 1..128: weight split. blocks 129+:
// zero sums + histH + histT (10000 u32).
__global__ __launch_bounds__(256) void k_init(const unsigned* __restrict__ xe_raw,
                                              const void* __restrict__ ah_in, const void* __restrict__ at_in,
                                              const void* __restrict__ wh, const void* __restrict__ wt,
                                              unsigned* __restrict__ flag, float* __restrict__ ah32,
                                              float* __restrict__ at32,
                                              __bf16* __restrict__ whh, __bf16* __restrict__ whl,
                                              __bf16* __restrict__ wth, __bf16* __restrict__ wtl,
                                              unsigned* __restrict__ zero1) {
    int isbf = sniff_isbf(xe_raw);
    int t = threadIdx.x;
    if (blockIdx.x == 0) {
        if (t == 0) flag[0] = (unsigned)isbf;
        ah32[t] = isbf ? __bfloat162float(((const __hip_bfloat16*)ah_in)[t]) : ((const float*)ah_in)[t];
        at32[t] = isbf ? __bfloat162float(((const __hip_bfloat16*)at_in)[t]) : ((const float*)at_in)[t];
    } else if (blockIdx.x <= 128) {
        int i = (blockIdx.x - 1) * 256 + t;   // [0, 32768)
        if (isbf) {
            whh[i] = ((const __bf16*)wh)[i]; whl[i] = (__bf16)0.f;
            wth[i] = ((const __bf16*)wt)[i]; wtl[i] = (__bf16)0.f;
        } else {
            float a = ((const float*)wh)[i];
            float b = ((const float*)wt)[i];
            __bf16 ah_ = (__bf16)a, bh_ = (__bf16)b;
            whh[i] = ah_; whl[i] = (__bf16)(a - (float)ah_);
            wth[i] = bh_; wtl[i] = (__bf16)(b - (float)bh_);
        }
    } else {
        int stride = (gridDim.x - 129) * 256;
        for (int i = (blockIdx.x - 129) * 256 + t; i < 10000; i += stride) zero1[i] = 0u;
    }
}

// LDS-staged GEMM: block tile 128x128, 4 waves x 32 rows (round-6 notes).
#define GM 128
#define WROW 40
__global__ __launch_bounds__(256, 2) void k_gemm(const void* __restrict__ xe,
                                                 const unsigned* __restrict__ flag,
                                                 const __bf16* __restrict__ whh, const __bf16* __restrict__ whl,
                                                 const __bf16* __restrict__ wth, const __bf16* __restrict__ wtl,
                                                 __hip_bfloat16* __restrict__ xh, __hip_bfloat16* __restrict__ xt) {
    const int isbf = (int)flag[0];
    __shared__ __bf16 sw[4][128 * WROW];
    int t = threadIdx.x;
    int lane = t & 63, wave = t >> 6;
    int quad = lane >> 4, l16 = lane & 15;
    int rowBase = blockIdx.x * GM + wave * 32;
    int r0 = rowBase + l16, r1 = r0 + 16;
    int ar0 = r0 < NN ? r0 : NN - 1;
    int ar1 = r1 < NN ? r1 : NN - 1;

    f32x4 accH0[8], accH1[8], accT0[8], accT1[8];
    for (int i = 0; i < 8; ++i) {
        accH0[i] = (f32x4){0.f,0.f,0.f,0.f}; accH1[i] = (f32x4){0.f,0.f,0.f,0.f};
        accT0[i] = (f32x4){0.f,0.f,0.f,0.f}; accT1[i] = (f32x4){0.f,0.f,0.f,0.f};
    }
    const int nparts = isbf ? 2 : 4;
    const __bf16* wsrc[4] = {whh, wth, whl, wtl};

    for (int ks = 0; ks < 8; ++ks) {
        int kb = ks * 32;
        __syncthreads();
        for (int part = 0; part < nparts; ++part) {
            const __bf16* wp = wsrc[part];
            for (int half = 0; half < 2; ++half) {
                int idx = half * 256 + t;
                int row = idx >> 2, ko = (idx & 3) * 8;
                uint4 v = *(const uint4*)(wp + (size_t)row * KEH + kb + ko);
                *(uint4*)(&sw[part][row * WROW + ko]) = v;
            }
        }
        __syncthreads();

        bf16x8 a0h, a0l, a1h, a1l;
        if (isbf) {
            a0h = *(const bf16x8*)((const __bf16*)xe + (size_t)ar0 * KEH + kb + quad * 8);
            a1h = *(const bf16x8*)((const __bf16*)xe + (size_t)ar1 * KEH + kb + quad * 8);
        } else {
            const float* p0 = (const float*)xe + (size_t)ar0 * KEH + kb + quad * 8;
            const float* p1 = (const float*)xe + (size_t)ar1 * KEH + kb + quad * 8;
            float4 u0 = *(const float4*)p0, u1 = *(const float4*)(p0 + 4);
            float4 w0 = *(const float4*)p1, w1 = *(const float4*)(p1 + 4);
            float v0[8] = {u0.x,u0.y,u0.z,u0.w,u1.x,u1.y,u1.z,u1.w};
            float v1[8] = {w0.x,w0.y,w0.z,w0.w,w1.x,w1.y,w1.z,w1.w};
            for (int j = 0; j < 8; ++j) {
                __bf16 h0 = (__bf16)v0[j], h1 = (__bf16)v1[j];
                a0h[j] = h0; a0l[j] = (__bf16)(v0[j] - (float)h0);
                a1h[j] = h1; a1l[j] = (__bf16)(v1[j] - (float)h1);
            }
        }
        for (int ct = 0; ct < 8; ++ct) {
            int fo = (ct * 16 + l16) * WROW + quad * 8;
            bf16x8 fh = *(const bf16x8*)(&sw[0][fo]);
            bf16x8 ft = *(const bf16x8*)(&sw[1][fo]);
            accH0[ct] = __builtin_amdgcn_mfma_f32_16x16x32_bf16(a0h, fh, accH0[ct], 0, 0, 0);
            accH1[ct] = __builtin_amdgcn_mfma_f32_16x16x32_bf16(a1h, fh, accH1[ct], 0, 0, 0);
            accT0[ct] = __builtin_amdgcn_mfma_f32_16x16x32_bf16(a0h, ft, accT0[ct], 0, 0, 0);
            accT1[ct] = __builtin_amdgcn_mfma_f32_16x16x32_bf16(a1h, ft, accT1[ct], 0, 0, 0);
            if (!isbf) {
                bf16x8 fhl = *(const bf16x8*)(&sw[2][fo]);
                bf16x8 ftl = *(const bf16x8*)(&sw[3][fo]);
                accH0[ct] = __builtin_amdgcn_mfma_f32_16x16x32_bf16(a0l, fh,  accH0[ct], 0, 0, 0);
                accH0[ct] = __builtin_amdgcn_mfma_f32_16x16x32_bf16(a0h, fhl, accH0[ct], 0, 0, 0);
                accH1[ct] = __builtin_amdgcn_mfma_f32_16x16x32_bf16(a1l, fh,  accH1[ct], 0, 0, 0);
                accH1[ct] = __builtin_amdgcn_mfma_f32_16x16x32_bf16(a1h, fhl, accH1[ct], 0, 0, 0);
                accT0[ct] = __builtin_amdgcn_mfma_f32_16x16x32_bf16(a0l, ft,  accT0[ct], 0, 0, 0);
                accT0[ct] = __builtin_amdgcn_mfma_f32_16x16x32_bf16(a0h, ftl, accT0[ct], 0, 0, 0);
                accT1[ct] = __builtin_amdgcn_mfma_f32_16x16x32_bf16(a1l, ft,  accT1[ct], 0, 0, 0);
                accT1[ct] = __builtin_amdgcn_mfma_f32_16x16x32_bf16(a1h, ftl, accT1[ct], 0, 0, 0);
            }
        }
    }
    for (int ct = 0; ct < 8; ++ct) {
        int col = ct * 16 + l16;
        for (int r2 = 0; r2 < 4; ++r2) {
            int o0 = rowBase + quad * 4 + r2;
            int o1 = o0 + 16;
            if (o0 < NN) {
                xh[(size_t)o0 * KRH + col] = __float2bfloat16(accH0[ct][r2]);
                xt[(size_t)o0 * KRH + col] = __float2bfloat16(accT0[ct][r2]);
            }
            if (o1 < NN) {
                xh[(size_t)o1 * KRH + col] = __float2bfloat16(accH1[ct][r2]);
                xt[(size_t)o1 * KRH + col] = __float2bfloat16(accT1[ct][r2]);
            }
        }
    }
}

// One wave per node: 8 dot products of length 128.
__global__ __launch_bounds__(256) void k_scores(const __hip_bfloat16* __restrict__ xh,
                                                const __hip_bfloat16* __restrict__ xt,
                                                const float* __restrict__ ah, const float* __restrict__ at,
                                                float4* __restrict__ sp, float4* __restrict__ dp) {
    int lane = threadIdx.x & 63;
    int w = threadIdx.x >> 6;
    int n = blockIdx.x * 4 + w;
    if (n >= NN) return;
    float xh0 = __bfloat162float(xh[(size_t)n*KRH + lane]);
    float xh1 = __bfloat162float(xh[(size_t)n*KRH + 64 + lane]);
    float xt0 = __bfloat162float(xt[(size_t)n*KRH + lane]);
    float xt1 = __bfloat162float(xt[(size_t)n*KRH + 64 + lane]);
    float ah00 = ah[lane],       ah01 = ah[64 + lane];
    float ah10 = ah[128 + lane], ah11 = ah[192 + lane];
    float at00 = at[lane],       at01 = at[64 + lane];
    float at10 = at[128 + lane], at11 = at[192 + lane];
    float v[8];
    v[0] = xh0*ah00 + xh1*ah01;
    v[1] = xh0*ah10 + xh1*ah11;
    v[2] = xt0*ah00 + xt1*ah01;
    v[3] = xt0*ah10 + xt1*ah11;
    v[4] = xt0*at00 + xt1*at01;
    v[5] = xt0*at10 + xt1*at11;
    v[6] = xh0*at00 + xh1*at01;
    v[7] = xh0*at10 + xh1*at11;
    for (int off = 32; off; off >>= 1)
        for (int j = 0; j < 8; ++j) v[j] += __shfl_xor(v[j], off);
    if (lane == 0) {
        sp[n] = make_float4(v[0], v[1], v[2], v[3]);
        dp[n] = make_float4(v[4], v[5], v[6], v[7]);
    }
}

__device__ __forceinline__ float eexp(float x) {
    x = x > 0.f ? x : 0.01f * x;
    x = fminf(x, 50.f);
    return __expf(x);
}

// Per edge (contiguous 3125-edge range per block): 4 exp scores -> LDS segment
// sums; (rel,sbin) local histograms -> global totals (atomic) AND this block's
// private hpb row (non-atomic, coalesced) for deterministic scatter offsets.
__global__ __launch_bounds__(256) void k_edge(const int* __restrict__ src, const int* __restrict__ dst,
                                              const int* __restrict__ rel,
                                              const float4* __restrict__ sp, const float4* __restrict__ dp,
                                              float* __restrict__ sums,
                                              unsigned* __restrict__ histH, unsigned* __restrict__ histT,
                                              unsigned* __restrict__ hpbH, unsigned* __restrict__ hpbT) {
    __shared__ float ls[NR * 4];
    __shared__ unsigned lhH[NBK], lhT[NBK];
    int t = threadIdx.x;
    for (int i = t; i < NR * 4; i += 256) ls[i] = 0.f;
    for (int i = t; i < NBK; i += 256) { lhH[i] = 0u; lhT[i] = 0u; }
    __syncthreads();
    unsigned lo = blockIdx.x * EPB, hi = lo + EPB;
    for (unsigned e = lo + t; e < hi; e += 256) {
        int s = clampi(src[e], NN), d = clampi(dst[e], NN), r = clampi(rel[e], NR);
        float4 a = sp[s], b = dp[d];
        atomicAdd(&ls[r*4+0], eexp(a.x + b.x));
        atomicAdd(&ls[r*4+1], eexp(a.y + b.y));
        atomicAdd(&ls[r*4+2], eexp(a.z + b.z));
        atomicAdd(&ls[r*4+3], eexp(a.w + b.w));
        atomicAdd(&lhH[r * NSB + s / SBW], 1u);
        atomicAdd(&lhT[r * NSB + d / SBW], 1u);
    }
    __syncthreads();
    for (int i = t; i < NR * 4; i += 256)
        if (ls[i] != 0.f) atomicAdd(&sums[i], ls[i]);
    size_t row = (size_t)blockIdx.x * NBK;
    for (int i = t; i < NBK; i += 256) {
        unsigned cH = lhH[i], cT = lhT[i];
        hpbH[row + i] = cH;
        hpbT[row + i] = cT;
        if (cH) atomicAdd(&histH[i], cH);
        if (cT) atomicAdd(&histT[i], cT);
    }
}

// Scan both 4000-bin total histograms -> bucket bases; invs = 1/(sums+eps).
__global__ __launch_bounds__(1024) void k_scan2(const unsigned* __restrict__ histH,
                                                const unsigned* __restrict__ histT,
                                                const float* __restrict__ sums,
                                                unsigned* __restrict__ baseH, unsigned* __restrict__ baseT,
                                                float* __restrict__ invs) {
    __shared__ unsigned sc[1024];
    int t = threadIdx.x;
    for (int pass = 0; pass < 2; ++pass) {
        const unsigned* h = pass ? histT : histH;
        unsigned* base = pass ? baseT : baseH;
        int j0 = t * 4;
        unsigned v[4], s = 0;
        for (int k = 0; k < 4; ++k) { v[k] = (j0 + k < NBK) ? h[j0 + k] : 0u; s += v[k]; }
        sc[t] = s;
        __syncthreads();
        for (int off = 1; off < 1024; off <<= 1) {
            unsigned add = (t >= off) ? sc[t - off] : 0u;
            __syncthreads();
            sc[t] += add;
            __syncthreads();
        }
        unsigned run = sc[t] - s;
        for (int k = 0; k < 4; ++k) {
            if (j0 + k < NBK) { base[j0 + k] = run; run += v[k]; }
        }
        if (t == 1023) base[NBK] = sc[1023];
        __syncthreads();
    }
    for (int i = t; i < NR * 4; i += 1024) invs[i] = 1.f / (sums[i] + 1e-16f);
}

// Column scan: per (pass,bin), exclusive-scan the NBE per-block counts and add
// the bucket base -> hpb becomes each block's exact write offset. No atomics.
__global__ __launch_bounds__(NBE) void k_colscan(unsigned* __restrict__ hpbH, unsigned* __restrict__ hpbT,
                                                 const unsigned* __restrict__ baseH,
                                                 const unsigned* __restrict__ baseT) {
    __shared__ unsigned sc[NBE];
    int b = blockIdx.x;              // [0, 2*NBK)
    int pass = b >= NBK;
    int bin = pass ? b - NBK : b;
    unsigned* h = pass ? hpbT : hpbH;
    unsigned basev = (pass ? baseT : baseH)[bin];
    int t = threadIdx.x;
    unsigned v = h[(size_t)t * NBK + bin];
    sc[t] = v;
    __syncthreads();
    for (int off = 1; off < NBE; off <<= 1) {
        unsigned add = (t >= off) ? sc[t - off] : 0u;
        __syncthreads();
        sc[t] += add;
        __syncthreads();
    }
    h[(size_t)t * NBK + bin] = basev + sc[t] - v;
}

// Single-pass scatter: load this block's offset rows into LDS, then for each
// edge compute softmax weights and write records. LDS cursors only.
__global__ __launch_bounds__(256) void k_mkrec(const int* __restrict__ src, const int* __restrict__ dst,
                                               const int* __restrict__ rel,
                                               const float4* __restrict__ sp, const float4* __restrict__ dp,
                                               const float4* __restrict__ invs4,
                                               const unsigned* __restrict__ hpbH, const unsigned* __restrict__ hpbT,
                                               uint2* __restrict__ recH, uint2* __restrict__ recT) {
    __shared__ unsigned lcH[NBK], lcT[NBK];
    int t = threadIdx.x;
    size_t row = (size_t)blockIdx.x * NBK;
    for (int i = t; i < NBK; i += 256) { lcH[i] = hpbH[row + i]; lcT[i] = hpbT[row + i]; }
    __syncthreads();
    unsigned lo = blockIdx.x * EPB, hi = lo + EPB;
    for (unsigned e = lo + t; e < hi; e += 256) {
        int s = clampi(src[e], NN), d = clampi(dst[e], NN), r = clampi(rel[e], NR);
        float4 a = sp[s], b = dp[d];
        float4 iv = invs4[r];
        float w1 = eexp(a.x + b.x) * iv.x + eexp(a.y + b.y) * iv.y;
        float w2 = eexp(a.z + b.z) * iv.z + eexp(a.w + b.w) * iv.w;
        unsigned pH = atomicAdd(&lcH[r * NSB + s / SBW], 1u);
        unsigned pT = atomicAdd(&lcT[r * NSB + d / SBW], 1u);
        if (pH < NE) recH[pH] = make_uint2((unsigned)s, __float_as_uint(w1));
        if (pT < NE) recT[pT] = make_uint2((unsigned)d, __float_as_uint(w2));
    }
}

// One block per (rel,sbin) bucket (round-8 notes): register accumulation,
// wave-uniform rec loads, non-atomic partial store.
__global__ __launch_bounds__(256) void k_accR(const uint2* __restrict__ recH, const uint2* __restrict__ recT,
                                              const unsigned* __restrict__ baseH, const unsigned* __restrict__ baseT,
                                              const __hip_bfloat16* __restrict__ xh,
                                              const __hip_bfloat16* __restrict__ xt,
                                              float* __restrict__ part) {
    __shared__ float red[4][128];
    int b = blockIdx.x;
    int t = threadIdx.x, lane = t & 63, wv = t >> 6;
    int c2 = lane * 2;
    float ax = 0.f, ay = 0.f;
    for (int pass = 0; pass < 2; ++pass) {
        const uint2* rec = pass ? recT : recH;
        const unsigned* base = pass ? baseT : baseH;
        const unsigned short* xs = (const unsigned short*)(pass ? xt : xh);
        unsigned b0 = base[b];
        unsigned cnt = base[b + 1] - b0;
        if (cnt > NE) cnt = 0;        // poison guard
        for (unsigned j = (unsigned)wv; j < cnt; j += 4) {
            uint2 rr = rec[b0 + j];   // wave-uniform address -> broadcast
            unsigned node = rr.x;
            if (node >= NN) node = 0;
            float w = __uint_as_float(rr.y);
            unsigned u = *(const unsigned*)(xs + (size_t)node * KRH + c2);
            ax = fmaf(w, __uint_as_float(u << 16), ax);
            ay = fmaf(w, __uint_as_float(u & 0xffff0000u), ay);
        }
    }
    red[wv][c2] = ax; red[wv][c2 + 1] = ay;
    __syncthreads();
    if (wv == 0) {
        float vx = red[0][c2] + red[1][c2] + red[2][c2] + red[3][c2];
        float vy = red[0][c2+1] + red[1][c2+1] + red[2][c2+1] + red[3][c2+1];
        *(float2*)(&part[(size_t)b * KRH + c2]) = make_float2(vx, vy);
    }
}

// out[r][c] = 0.25 * sum_sbin part[r*8+sbin][c]; dtype follows input.
__global__ __launch_bounds__(256) void k_out(const float* __restrict__ part,
                                             const unsigned* __restrict__ flag, void* __restrict__ out) {
    int i = blockIdx.x * 256 + threadIdx.x;
    if (i < NR * KRH) {
        int r = i >> 7, c = i & 127;
        float v = 0.f;
        for (int s = 0; s < NSB; ++s) v += part[(size_t)(r * NSB + s) * KRH + c];
        v *= 0.25f;                   // / num_heads(2) / 2
        if (!isfinite(v)) v = 0.f;
        if (flag[0]) ((__hip_bfloat16*)out)[i] = __float2bfloat16(v);
        else         ((float*)out)[i] = v;
    }
}

extern "C" void kernel_launch(void* const* d_in, const int* in_sizes, int n_in,
                              void* d_out, int out_size, void* d_ws, size_t ws_size,
                              hipStream_t stream) {
    const void* xe  = d_in[0];
    const int* eidx = (const int*)d_in[1];
    const int* rel  = (const int*)d_in[2];
    const void* wh  = d_in[3];
    const void* wt  = d_in[4];
    const void* ahp = d_in[5];
    const void* atp = d_in[6];

    const int* src = eidx;
    const int* dst = eidx + NE;

    char* ws = (char*)d_ws;
    __hip_bfloat16* xh = (__hip_bfloat16*)(ws + OFF_XH);
    __hip_bfloat16* xt = (__hip_bfloat16*)(ws + OFF_XT);
    float4*   sp     = (float4*)(ws + OFF_SP);
    float4*   dp     = (float4*)(ws + OFF_DP);
    float*    sums   = (float*)(ws + OFF_SUMS);
    unsigned* histH  = (unsigned*)(ws + OFF_HISTH);
    unsigned* histT  = (unsigned*)(ws + OFF_HISTT);
    float*    invs   = (float*)(ws + OFF_INVS);
    unsigned* baseH  = (unsigned*)(ws + OFF_BASEH);
    unsigned* baseT  = (unsigned*)(ws + OFF_BASET);
    uint2*    recH   = (uint2*)(ws + OFF_RECH);
    uint2*    recT   = (uint2*)(ws + OFF_RECT);
    float*    partp  = (float*)(ws + OFF_PART);
    float*    ah32   = (float*)(ws + OFF_AH);
    float*    at32   = (float*)(ws + OFF_AT);
    unsigned* flag   = (unsigned*)(ws + OFF_FLAG);
    __bf16*   whh    = (__bf16*)(ws + OFF_WHH);
    __bf16*   whl    = (__bf16*)(ws + OFF_WHL);
    __bf16*   wth    = (__bf16*)(ws + OFF_WTH);
    __bf16*   wtl    = (__bf16*)(ws + OFF_WTL);
    unsigned* hpbH   = (unsigned*)(ws + OFF_HPBH);
    unsigned* hpbT   = (unsigned*)(ws + OFF_HPBT);

    k_init<<<161, 256, 0, stream>>>((const unsigned*)xe, ahp, atp, wh, wt, flag, ah32, at32,
                                     whh, whl, wth, wtl, (unsigned*)(ws + OFF_SUMS));
    k_gemm<<<(NN + GM - 1) / GM, 256, 0, stream>>>(xe, flag, whh, whl, wth, wtl, xh, xt);
    k_scores<<<(NN + 3) / 4, 256, 0, stream>>>(xh, xt, ah32, at32, sp, dp);
    k_edge<<<NBE, 256, 0, stream>>>(src, dst, rel, sp, dp, sums, histH, histT, hpbH, hpbT);
    k_scan2<<<1, 1024, 0, stream>>>(histH, histT, sums, baseH, baseT, invs);
    k_colscan<<<2 * NBK, NBE, 0, stream>>>(hpbH, hpbT, baseH, baseT);
    k_mkrec<<<NBE, 256, 0, stream>>>(src, dst, rel, sp, dp, (const float4*)invs, hpbH, hpbT, recH, recT);
    k_accR<<<NBK, 256, 0, stream>>>(recH, recT, baseH, baseT, xh, xt, partp);
    k_out<<<(NR * KRH + 255) / 256, 256, 0, stream>>>(partp, flag, d_out);
}

// Round 11
// 335.793 us; speedup vs baseline: 4.9113x; 1.1006x over previous
//
#include <hip/hip_runtime.h>
#include <hip/hip_bf16.h>

#define NN 50000      // nodes
#define NE 800000     // edges
#define NR 500        // relations
#define KEH 256       // input feat dim
#define KRH 128       // proj feat dim
#define NSB 8         // node super-bins (node / 6250), aligned to 8 XCDs
#define SBW 6250      // super-bin width
#define NBK (NR*NSB)  // 4000 buckets
#define NBE 256       // edge-pass blocks (k_edge / k_mkrec)
#define EPB (NE/NBE)  // 3125 edges per block

typedef __attribute__((ext_vector_type(8))) __bf16 bf16x8;
typedef __attribute__((ext_vector_type(4))) float f32x4;

// ---- workspace layout (bytes, 16B aligned), total ~50.6 MiB ----
#define OFF_XH     0UL            // [NN][128] bf16
#define OFF_XT     12800000UL     // [NN][128] bf16
#define OFF_SP     25600000UL     // [NN] float4
#define OFF_DP     26400000UL     // [NN] float4
#define OFF_SUMS   27200000UL     // [NR*4] f32 (8000 B)
#define OFF_HISTH  27208000UL     // [NBK] u32 totals (16000 B)
#define OFF_HISTT  27224000UL     // [NBK] u32 totals (16000 B)
// zero region SUMS..HISTT = 40000 B = 10000 u32
#define OFF_INVS   27240000UL     // [NR*4] f32
#define OFF_BASEH  27248000UL     // [NBK+1] u32 (16016 B)
#define OFF_BASET  27264016UL     // [NBK+1] u32
#define OFF_RECH   27312032UL     // [NE] uint2 (node, w1) 6.4 MB
#define OFF_RECT   33712032UL     // [NE] uint2 (node, w2) 6.4 MB
#define OFF_PART   40112032UL     // [NBK][128] f32 partials (2.048 MB)
#define OFF_AH     42160032UL     // [256] f32
#define OFF_AT     42161056UL     // [256] f32
#define OFF_FLAG   42162080UL     // u32
#define OFF_WHH    42162144UL     // [128][256] bf16
#define OFF_WHL    42227680UL
#define OFF_WTH    42293216UL
#define OFF_WTL    42358752UL
#define OFF_HPBH   42424288UL     // [NBE][NBK] u32 per-block hist/offsets 4.096 MB
#define OFF_HPBT   46520288UL     // [NBE][NBK] u32                       4.096 MB
// end 50,616,288

__device__ __forceinline__ int clampi(int v, int hi) {  // [0, hi)
    v = v < 0 ? 0 : v;
    return v >= hi ? hi - 1 : v;
}

// Wave-replicated dtype sniff (see round-8 notes).
__device__ __forceinline__ int sniff_isbf(const unsigned* xe_raw) {
    int lane = threadIdx.x & 63;
    unsigned w = xe_raw[lane];
    unsigned ex = (w >> 7) & 0xFFu;
    bool hit = (ex >= 115u && ex <= 131u);
    return __popcll(__ballot(hit)) >= 32;
}

// block 0: flag + a_h/a_t convert. blocks 1..128: weight split. blocks 129+:
// zero sums + histH + histT (10000 u32).
__global__ __launch_bounds__(256) void k_init(const unsigned* __restrict__ xe_raw,
                                              const void* __restrict__ ah_in, const void* __restrict__ at_in,
                                              const void* __restrict__ wh, const void* __restrict__ wt,
                                              unsigned* __restrict__ flag, float* __restrict__ ah32,
                                              float* __restrict__ at32,
                                              __bf16* __restrict__ whh, __bf16* __restrict__ whl,
                                              __bf16* __restrict__ wth, __bf16* __restrict__ wtl,
                                              unsigned* __restrict__ zero1) {
    int isbf = sniff_isbf(xe_raw);
    int t = threadIdx.x;
    if (blockIdx.x == 0) {
        if (t == 0) flag[0] = (unsigned)isbf;
        ah32[t] = isbf ? __bfloat162float(((const __hip_bfloat16*)ah_in)[t]) : ((const float*)ah_in)[t];
        at32[t] = isbf ? __bfloat162float(((const __hip_bfloat16*)at_in)[t]) : ((const float*)at_in)[t];
    } else if (blockIdx.x <= 128) {
        int i = (blockIdx.x - 1) * 256 + t;   // [0, 32768)
        if (isbf) {
            whh[i] = ((const __bf16*)wh)[i]; whl[i] = (__bf16)0.f;
            wth[i] = ((const __bf16*)wt)[i]; wtl[i] = (__bf16)0.f;
        } else {
            float a = ((const float*)wh)[i];
            float b = ((const float*)wt)[i];
            __bf16 ah_ = (__bf16)a, bh_ = (__bf16)b;
            whh[i] = ah_; whl[i] = (__bf16)(a - (float)ah_);
            wth[i] = bh_; wtl[i] = (__bf16)(b - (float)bh_);
        }
    } else {
        int stride = (gridDim.x - 129) * 256;
        for (int i = (blockIdx.x - 129) * 256 + t; i < 10000; i += stride) zero1[i] = 0u;
    }
}

// LDS-staged GEMM: block tile 128x128, 4 waves x 32 rows (round-6 notes).
#define GM 128
#define WROW 40
__global__ __launch_bounds__(256, 2) void k_gemm(const void* __restrict__ xe,
                                                 const unsigned* __restrict__ flag,
                                                 const __bf16* __restrict__ whh, const __bf16* __restrict__ whl,
                                                 const __bf16* __restrict__ wth, const __bf16* __restrict__ wtl,
                                                 __hip_bfloat16* __restrict__ xh, __hip_bfloat16* __restrict__ xt) {
    const int isbf = (int)flag[0];
    __shared__ __bf16 sw[4][128 * WROW];
    int t = threadIdx.x;
    int lane = t & 63, wave = t >> 6;
    int quad = lane >> 4, l16 = lane & 15;
    int rowBase = blockIdx.x * GM + wave * 32;
    int r0 = rowBase + l16, r1 = r0 + 16;
    int ar0 = r0 < NN ? r0 : NN - 1;
    int ar1 = r1 < NN ? r1 : NN - 1;

    f32x4 accH0[8], accH1[8], accT0[8], accT1[8];
    for (int i = 0; i < 8; ++i) {
        accH0[i] = (f32x4){0.f,0.f,0.f,0.f}; accH1[i] = (f32x4){0.f,0.f,0.f,0.f};
        accT0[i] = (f32x4){0.f,0.f,0.f,0.f}; accT1[i] = (f32x4){0.f,0.f,0.f,0.f};
    }
    const int nparts = isbf ? 2 : 4;
    const __bf16* wsrc[4] = {whh, wth, whl, wtl};

    for (int ks = 0; ks < 8; ++ks) {
        int kb = ks * 32;
        __syncthreads();
        for (int part = 0; part < nparts; ++part) {
            const __bf16* wp = wsrc[part];
            for (int half = 0; half < 2; ++half) {
                int idx = half * 256 + t;
                int row = idx >> 2, ko = (idx & 3) * 8;
                uint4 v = *(const uint4*)(wp + (size_t)row * KEH + kb + ko);
                *(uint4*)(&sw[part][row * WROW + ko]) = v;
            }
        }
        __syncthreads();

        bf16x8 a0h, a0l, a1h, a1l;
        if (isbf) {
            a0h = *(const bf16x8*)((const __bf16*)xe + (size_t)ar0 * KEH + kb + quad * 8);
            a1h = *(const bf16x8*)((const __bf16*)xe + (size_t)ar1 * KEH + kb + quad * 8);
        } else {
            const float* p0 = (const float*)xe + (size_t)ar0 * KEH + kb + quad * 8;
            const float* p1 = (const float*)xe + (size_t)ar1 * KEH + kb + quad * 8;
            float4 u0 = *(const float4*)p0, u1 = *(const float4*)(p0 + 4);
            float4 w0 = *(const float4*)p1, w1 = *(const float4*)(p1 + 4);
            float v0[8] = {u0.x,u0.y,u0.z,u0.w,u1.x,u1.y,u1.z,u1.w};
            float v1[8] = {w0.x,w0.y,w0.z,w0.w,w1.x,w1.y,w1.z,w1.w};
            for (int j = 0; j < 8; ++j) {
                __bf16 h0 = (__bf16)v0[j], h1 = (__bf16)v1[j];
                a0h[j] = h0; a0l[j] = (__bf16)(v0[j] - (float)h0);
                a1h[j] = h1; a1l[j] = (__bf16)(v1[j] - (float)h1);
            }
        }
        for (int ct = 0; ct < 8; ++ct) {
            int fo = (ct * 16 + l16) * WROW + quad * 8;
            bf16x8 fh = *(const bf16x8*)(&sw[0][fo]);
            bf16x8 ft = *(const bf16x8*)(&sw[1][fo]);
            accH0[ct] = __builtin_amdgcn_mfma_f32_16x16x32_bf16(a0h, fh, accH0[ct], 0, 0, 0);
            accH1[ct] = __builtin_amdgcn_mfma_f32_16x16x32_bf16(a1h, fh, accH1[ct], 0, 0, 0);
            accT0[ct] = __builtin_amdgcn_mfma_f32_16x16x32_bf16(a0h, ft, accT0[ct], 0, 0, 0);
            accT1[ct] = __builtin_amdgcn_mfma_f32_16x16x32_bf16(a1h, ft, accT1[ct], 0, 0, 0);
            if (!isbf) {
                bf16x8 fhl = *(const bf16x8*)(&sw[2][fo]);
                bf16x8 ftl = *(const bf16x8*)(&sw[3][fo]);
                accH0[ct] = __builtin_amdgcn_mfma_f32_16x16x32_bf16(a0l, fh,  accH0[ct], 0, 0, 0);
                accH0[ct] = __builtin_amdgcn_mfma_f32_16x16x32_bf16(a0h, fhl, accH0[ct], 0, 0, 0);
                accH1[ct] = __builtin_amdgcn_mfma_f32_16x16x32_bf16(a1l, fh,  accH1[ct], 0, 0, 0);
                accH1[ct] = __builtin_amdgcn_mfma_f32_16x16x32_bf16(a1h, fhl, accH1[ct], 0, 0, 0);
                accT0[ct] = __builtin_amdgcn_mfma_f32_16x16x32_bf16(a0l, ft,  accT0[ct], 0, 0, 0);
                accT0[ct] = __builtin_amdgcn_mfma_f32_16x16x32_bf16(a0h, ftl, accT0[ct], 0, 0, 0);
                accT1[ct] = __builtin_amdgcn_mfma_f32_16x16x32_bf16(a1l, ft,  accT1[ct], 0, 0, 0);
                accT1[ct] = __builtin_amdgcn_mfma_f32_16x16x32_bf16(a1h, ftl, accT1[ct], 0, 0, 0);
            }
        }
    }
    for (int ct = 0; ct < 8; ++ct) {
        int col = ct * 16 + l16;
        for (int r2 = 0; r2 < 4; ++r2) {
            int o0 = rowBase + quad * 4 + r2;
            int o1 = o0 + 16;
            if (o0 < NN) {
                xh[(size_t)o0 * KRH + col] = __float2bfloat16(accH0[ct][r2]);
                xt[(size_t)o0 * KRH + col] = __float2bfloat16(accT0[ct][r2]);
            }
            if (o1 < NN) {
                xh[(size_t)o1 * KRH + col] = __float2bfloat16(accH1[ct][r2]);
                xt[(size_t)o1 * KRH + col] = __float2bfloat16(accT1[ct][r2]);
            }
        }
    }
}

// One wave per node: 8 dot products of length 128.
__global__ __launch_bounds__(256) void k_scores(const __hip_bfloat16* __restrict__ xh,
                                                const __hip_bfloat16* __restrict__ xt,
                                                const float* __restrict__ ah, const float* __restrict__ at,
                                                float4* __restrict__ sp, float4* __restrict__ dp) {
    int lane = threadIdx.x & 63;
    int w = threadIdx.x >> 6;
    int n = blockIdx.x * 4 + w;
    if (n >= NN) return;
    float xh0 = __bfloat162float(xh[(size_t)n*KRH + lane]);
    float xh1 = __bfloat162float(xh[(size_t)n*KRH + 64 + lane]);
    float xt0 = __bfloat162float(xt[(size_t)n*KRH + lane]);
    float xt1 = __bfloat162float(xt[(size_t)n*KRH + 64 + lane]);
    float ah00 = ah[lane],       ah01 = ah[64 + lane];
    float ah10 = ah[128 + lane], ah11 = ah[192 + lane];
    float at00 = at[lane],       at01 = at[64 + lane];
    float at10 = at[128 + lane], at11 = at[192 + lane];
    float v[8];
    v[0] = xh0*ah00 + xh1*ah01;
    v[1] = xh0*ah10 + xh1*ah11;
    v[2] = xt0*ah00 + xt1*ah01;
    v[3] = xt0*ah10 + xt1*ah11;
    v[4] = xt0*at00 + xt1*at01;
    v[5] = xt0*at10 + xt1*at11;
    v[6] = xh0*at00 + xh1*at01;
    v[7] = xh0*at10 + xh1*at11;
    for (int off = 32; off; off >>= 1)
        for (int j = 0; j < 8; ++j) v[j] += __shfl_xor(v[j], off);
    if (lane == 0) {
        sp[n] = make_float4(v[0], v[1], v[2], v[3]);
        dp[n] = make_float4(v[4], v[5], v[6], v[7]);
    }
}

__device__ __forceinline__ float eexp(float x) {
    x = x > 0.f ? x : 0.01f * x;
    x = fminf(x, 50.f);
    return __expf(x);
}

// Per edge (contiguous 3125-edge range per block): 4 exp scores -> LDS segment
// sums; (rel,sbin) local histograms -> global totals (atomic) AND this block's
// private hpb row (non-atomic, coalesced) for deterministic scatter offsets.
__global__ __launch_bounds__(256) void k_edge(const int* __restrict__ src, const int* __restrict__ dst,
                                              const int* __restrict__ rel,
                                              const float4* __restrict__ sp, const float4* __restrict__ dp,
                                              float* __restrict__ sums,
                                              unsigned* __restrict__ histH, unsigned* __restrict__ histT,
                                              unsigned* __restrict__ hpbH, unsigned* __restrict__ hpbT) {
    __shared__ float ls[NR * 4];
    __shared__ unsigned lhH[NBK], lhT[NBK];
    int t = threadIdx.x;
    for (int i = t; i < NR * 4; i += 256) ls[i] = 0.f;
    for (int i = t; i < NBK; i += 256) { lhH[i] = 0u; lhT[i] = 0u; }
    __syncthreads();
    unsigned lo = blockIdx.x * EPB, hi = lo + EPB;
    for (unsigned e = lo + t; e < hi; e += 256) {
        int s = clampi(src[e], NN), d = clampi(dst[e], NN), r = clampi(rel[e], NR);
        float4 a = sp[s], b = dp[d];
        atomicAdd(&ls[r*4+0], eexp(a.x + b.x));
        atomicAdd(&ls[r*4+1], eexp(a.y + b.y));
        atomicAdd(&ls[r*4+2], eexp(a.z + b.z));
        atomicAdd(&ls[r*4+3], eexp(a.w + b.w));
        atomicAdd(&lhH[r * NSB + s / SBW], 1u);
        atomicAdd(&lhT[r * NSB + d / SBW], 1u);
    }
    __syncthreads();
    for (int i = t; i < NR * 4; i += 256)
        if (ls[i] != 0.f) atomicAdd(&sums[i], ls[i]);
    size_t row = (size_t)blockIdx.x * NBK;
    for (int i = t; i < NBK; i += 256) {
        unsigned cH = lhH[i], cT = lhT[i];
        hpbH[row + i] = cH;
        hpbT[row + i] = cT;
        if (cH) atomicAdd(&histH[i], cH);
        if (cT) atomicAdd(&histT[i], cT);
    }
}

// Scan both 4000-bin total histograms -> bucket bases; invs = 1/(sums+eps).
__global__ __launch_bounds__(1024) void k_scan2(const unsigned* __restrict__ histH,
                                                const unsigned* __restrict__ histT,
                                                const float* __restrict__ sums,
                                                unsigned* __restrict__ baseH, unsigned* __restrict__ baseT,
                                                float* __restrict__ invs) {
    __shared__ unsigned sc[1024];
    int t = threadIdx.x;
    for (int pass = 0; pass < 2; ++pass) {
        const unsigned* h = pass ? histT : histH;
        unsigned* base = pass ? baseT : baseH;
        int j0 = t * 4;
        unsigned v[4], s = 0;
        for (int k = 0; k < 4; ++k) { v[k] = (j0 + k < NBK) ? h[j0 + k] : 0u; s += v[k]; }
        sc[t] = s;
        __syncthreads();
        for (int off = 1; off < 1024; off <<= 1) {
            unsigned add = (t >= off) ? sc[t - off] : 0u;
            __syncthreads();
            sc[t] += add;
            __syncthreads();
        }
        unsigned run = sc[t] - s;
        for (int k = 0; k < 4; ++k) {
            if (j0 + k < NBK) { base[j0 + k] = run; run += v[k]; }
        }
        if (t == 1023) base[NBK] = sc[1023];
        __syncthreads();
    }
    for (int i = t; i < NR * 4; i += 1024) invs[i] = 1.f / (sums[i] + 1e-16f);
}

// Column scan: per (pass,bin), exclusive-scan the NBE per-block counts and add
// the bucket base -> hpb becomes each block's exact write offset. No atomics.
__global__ __launch_bounds__(NBE) void k_colscan(unsigned* __restrict__ hpbH, unsigned* __restrict__ hpbT,
                                                 const unsigned* __restrict__ baseH,
                                                 const unsigned* __restrict__ baseT) {
    __shared__ unsigned sc[NBE];
    int b = blockIdx.x;              // [0, 2*NBK)
    int pass = b >= NBK;
    int bin = pass ? b - NBK : b;
    unsigned* h = pass ? hpbT : hpbH;
    unsigned basev = (pass ? baseT : baseH)[bin];
    int t = threadIdx.x;
    unsigned v = h[(size_t)t * NBK + bin];
    sc[t] = v;
    __syncthreads();
    for (int off = 1; off < NBE; off <<= 1) {
        unsigned add = (t >= off) ? sc[t - off] : 0u;
        __syncthreads();
        sc[t] += add;
        __syncthreads();
    }
    h[(size_t)t * NBK + bin] = basev + sc[t] - v;
}

// Single-pass scatter: load this block's offset rows into LDS, then for each
// edge compute softmax weights and write records. LDS cursors only.
__global__ __launch_bounds__(256) void k_mkrec(const int* __restrict__ src, const int* __restrict__ dst,
                                               const int* __restrict__ rel,
                                               const float4* __restrict__ sp, const float4* __restrict__ dp,
                                               const float4* __restrict__ invs4,
                                               const unsigned* __restrict__ hpbH, const unsigned* __restrict__ hpbT,
                                               uint2* __restrict__ recH, uint2* __restrict__ recT) {
    __shared__ unsigned lcH[NBK], lcT[NBK];
    int t = threadIdx.x;
    size_t row = (size_t)blockIdx.x * NBK;
    for (int i = t; i < NBK; i += 256) { lcH[i] = hpbH[row + i]; lcT[i] = hpbT[row + i]; }
    __syncthreads();
    unsigned lo = blockIdx.x * EPB, hi = lo + EPB;
    for (unsigned e = lo + t; e < hi; e += 256) {
        int s = clampi(src[e], NN), d = clampi(dst[e], NN), r = clampi(rel[e], NR);
        float4 a = sp[s], b = dp[d];
        float4 iv = invs4[r];
        float w1 = eexp(a.x + b.x) * iv.x + eexp(a.y + b.y) * iv.y;
        float w2 = eexp(a.z + b.z) * iv.z + eexp(a.w + b.w) * iv.w;
        unsigned pH = atomicAdd(&lcH[r * NSB + s / SBW], 1u);
        unsigned pT = atomicAdd(&lcT[r * NSB + d / SBW], 1u);
        if (pH < NE) recH[pH] = make_uint2((unsigned)s, __float_as_uint(w1));
        if (pT < NE) recT[pT] = make_uint2((unsigned)d, __float_as_uint(w2));
    }
}

// One block per (rel,sbin) bucket. 4-wide unrolled edge loop: 4 independent
// rec loads then 4 independent row-gathers in flight per wave (breaks the
// 2-deep serial latency chain that bound round-10 at ~1000 cyc/edge).
__global__ __launch_bounds__(256) void k_accR(const uint2* __restrict__ recH, const uint2* __restrict__ recT,
                                              const unsigned* __restrict__ baseH, const unsigned* __restrict__ baseT,
                                              const __hip_bfloat16* __restrict__ xh,
                                              const __hip_bfloat16* __restrict__ xt,
                                              float* __restrict__ part) {
    __shared__ float red[4][128];
    int b = blockIdx.x;
    int t = threadIdx.x, lane = t & 63, wv = t >> 6;
    int c2 = lane * 2;
    float ax = 0.f, ay = 0.f;
    for (int pass = 0; pass < 2; ++pass) {
        const uint2* rec = pass ? recT : recH;
        const unsigned* base = pass ? baseT : baseH;
        const unsigned short* xs = (const unsigned short*)(pass ? xt : xh);
        unsigned b0 = base[b];
        unsigned cnt = base[b + 1] - b0;
        if (cnt > NE) cnt = 0;        // poison guard
        for (unsigned j = (unsigned)wv; j < cnt; j += 16) {
            unsigned i1 = j + 4, i2 = j + 8, i3 = j + 12;
            bool m1 = i1 < cnt, m2 = i2 < cnt, m3 = i3 < cnt;
            // 4 independent rec loads (wave-uniform -> broadcast), issued together
            uint2 r0 = rec[b0 + j];
            uint2 r1 = rec[b0 + (m1 ? i1 : j)];
            uint2 r2 = rec[b0 + (m2 ? i2 : j)];
            uint2 r3 = rec[b0 + (m3 ? i3 : j)];
            unsigned n0 = r0.x < NN ? r0.x : 0u;
            unsigned n1 = r1.x < NN ? r1.x : 0u;
            unsigned n2 = r2.x < NN ? r2.x : 0u;
            unsigned n3 = r3.x < NN ? r3.x : 0u;
            float w0 = __uint_as_float(r0.y);
            float w1 = m1 ? __uint_as_float(r1.y) : 0.f;
            float w2 = m2 ? __uint_as_float(r2.y) : 0.f;
            float w3 = m3 ? __uint_as_float(r3.y) : 0.f;
            // 4 independent row-gathers (4B/lane, coalesced per wave)
            unsigned u0 = *(const unsigned*)(xs + (size_t)n0 * KRH + c2);
            unsigned u1 = *(const unsigned*)(xs + (size_t)n1 * KRH + c2);
            unsigned u2 = *(const unsigned*)(xs + (size_t)n2 * KRH + c2);
            unsigned u3 = *(const unsigned*)(xs + (size_t)n3 * KRH + c2);
            ax = fmaf(w0, __uint_as_float(u0 << 16), ax);
            ay = fmaf(w0, __uint_as_float(u0 & 0xffff0000u), ay);
            ax = fmaf(w1, __uint_as_float(u1 << 16), ax);
            ay = fmaf(w1, __uint_as_float(u1 & 0xffff0000u), ay);
            ax = fmaf(w2, __uint_as_float(u2 << 16), ax);
            ay = fmaf(w2, __uint_as_float(u2 & 0xffff0000u), ay);
            ax = fmaf(w3, __uint_as_float(u3 << 16), ax);
            ay = fmaf(w3, __uint_as_float(u3 & 0xffff0000u), ay);
        }
    }
    red[wv][c2] = ax; red[wv][c2 + 1] = ay;
    __syncthreads();
    if (wv == 0) {
        float vx = red[0][c2] + red[1][c2] + red[2][c2] + red[3][c2];
        float vy = red[0][c2+1] + red[1][c2+1] + red[2][c2+1] + red[3][c2+1];
        *(float2*)(&part[(size_t)b * KRH + c2]) = make_float2(vx, vy);
    }
}

// out[r][c] = 0.25 * sum_sbin part[r*8+sbin][c]; dtype follows input.
__global__ __launch_bounds__(256) void k_out(const float* __restrict__ part,
                                             const unsigned* __restrict__ flag, void* __restrict__ out) {
    int i = blockIdx.x * 256 + threadIdx.x;
    if (i < NR * KRH) {
        int r = i >> 7, c = i & 127;
        float v = 0.f;
        for (int s = 0; s < NSB; ++s) v += part[(size_t)(r * NSB + s) * KRH + c];
        v *= 0.25f;                   // / num_heads(2) / 2
        if (!isfinite(v)) v = 0.f;
        if (flag[0]) ((__hip_bfloat16*)out)[i] = __float2bfloat16(v);
        else         ((float*)out)[i] = v;
    }
}

extern "C" void kernel_launch(void* const* d_in, const int* in_sizes, int n_in,
                              void* d_out, int out_size, void* d_ws, size_t ws_size,
                              hipStream_t stream) {
    const void* xe  = d_in[0];
    const int* eidx = (const int*)d_in[1];
    const int* rel  = (const int*)d_in[2];
    const void* wh  = d_in[3];
    const void* wt  = d_in[4];
    const void* ahp = d_in[5];
    const void* atp = d_in[6];

    const int* src = eidx;
    const int* dst = eidx + NE;

    char* ws = (char*)d_ws;
    __hip_bfloat16* xh = (__hip_bfloat16*)(ws + OFF_XH);
    __hip_bfloat16* xt = (__hip_bfloat16*)(ws + OFF_XT);
    float4*   sp     = (float4*)(ws + OFF_SP);
    float4*   dp     = (float4*)(ws + OFF_DP);
    float*    sums   = (float*)(ws + OFF_SUMS);
    unsigned* histH  = (unsigned*)(ws + OFF_HISTH);
    unsigned* histT  = (unsigned*)(ws + OFF_HISTT);
    float*    invs   = (float*)(ws + OFF_INVS);
    unsigned* baseH  = (unsigned*)(ws + OFF_BASEH);
    unsigned* baseT  = (unsigned*)(ws + OFF_BASET);
    uint2*    recH   = (uint2*)(ws + OFF_RECH);
    uint2*    recT   = (uint2*)(ws + OFF_RECT);
    float*    partp  = (float*)(ws + OFF_PART);
    float*    ah32   = (float*)(ws + OFF_AH);
    float*    at32   = (float*)(ws + OFF_AT);
    unsigned* flag   = (unsigned*)(ws + OFF_FLAG);
    __bf16*   whh    = (__bf16*)(ws + OFF_WHH);
    __bf16*   whl    = (__bf16*)(ws + OFF_WHL);
    __bf16*   wth    = (__bf16*)(ws + OFF_WTH);
    __bf16*   wtl    = (__bf16*)(ws + OFF_WTL);
    unsigned* hpbH   = (unsigned*)(ws + OFF_HPBH);
    unsigned* hpbT   = (unsigned*)(ws + OFF_HPBT);

    k_init<<<161, 256, 0, stream>>>((const unsigned*)xe, ahp, atp, wh, wt, flag, ah32, at32,
                                     whh, whl, wth, wtl, (unsigned*)(ws + OFF_SUMS));
    k_gemm<<<(NN + GM - 1) / GM, 256, 0, stream>>>(xe, flag, whh, whl, wth, wtl, xh, xt);
    k_scores<<<(NN + 3) / 4, 256, 0, stream>>>(xh, xt, ah32, at32, sp, dp);
    k_edge<<<NBE, 256, 0, stream>>>(src, dst, rel, sp, dp, sums, histH, histT, hpbH, hpbT);
    k_scan2<<<1, 1024, 0, stream>>>(histH, histT, sums, baseH, baseT, invs);
    k_colscan<<<2 * NBK, NBE, 0, stream>>>(hpbH, hpbT, baseH, baseT);
    k_mkrec<<<NBE, 256, 0, stream>>>(src, dst, rel, sp, dp, (const float4*)invs, hpbH, hpbT, recH, recT);
    k_accR<<<NBK, 256, 0, stream>>>(recH, recT, baseH, baseT, xh, xt, partp);
    k_out<<<(NR * KRH + 255) / 256, 256, 0, stream>>>(partp, flag, d_out);
}

// Round 12
// 300.383 us; speedup vs baseline: 5.4902x; 1.1179x over previous
//
#include <hip/hip_runtime.h>
#include <hip/hip_bf16.h>

#define NN 50000      // nodes
#define NE 800000     // edges
#define NR 500        // relations
#define KEH 256       // input feat dim
#define KRH 128       // proj feat dim
#define NSB 8         // node super-bins (node / 6250), aligned to 8 XCDs
#define SBW 6250      // super-bin width
#define NBK (NR*NSB)  // 4000 buckets
#define NBE 256       // edge-pass blocks (k_edge / k_mkrec)
#define EPB (NE/NBE)  // 3125 edges per block

typedef __attribute__((ext_vector_type(8))) __bf16 bf16x8;
typedef __attribute__((ext_vector_type(4))) float f32x4;

// ---- workspace layout (bytes, 16B aligned), total ~63.4 MiB ----
#define OFF_XH     0UL            // [NN][128] bf16
#define OFF_XT     12800000UL     // [NN][128] bf16
#define OFF_SP     25600000UL     // [NN] float4
#define OFF_DP     26400000UL     // [NN] float4
#define OFF_SUMS   27200000UL     // [NR*4] f32 (8000 B)
#define OFF_HISTH  27208000UL     // [NBK] u32 totals (16000 B)
#define OFF_HISTT  27224000UL     // [NBK] u32 totals (16000 B)
// zero region SUMS..HISTT = 40000 B = 10000 u32
#define OFF_INVS   27240000UL     // [NR*4] f32
#define OFF_BASEH  27248000UL     // [NBK+1] u32 (16016 B)
#define OFF_BASET  27264016UL     // [NBK+1] u32
#define OFF_RECH   27312032UL     // [NE] uint2 (node, w1) 6.4 MB
#define OFF_RECT   33712032UL     // [NE] uint2 (node, w2) 6.4 MB
#define OFF_PART   40112032UL     // [NBK][128] f32 partials (2.048 MB)
#define OFF_AH     42160032UL     // [256] f32
#define OFF_AT     42161056UL     // [256] f32
#define OFF_FLAG   42162080UL     // u32
#define OFF_WHH    42162144UL     // [128][256] bf16
#define OFF_WHL    42227680UL
#define OFF_WTH    42293216UL
#define OFF_WTL    42358752UL
#define OFF_HPBH   42424288UL     // [NBE][NBK] u32 per-block hist/offsets 4.096 MB
#define OFF_HPBT   46520288UL     // [NBE][NBK] u32                       4.096 MB
#define OFF_EX     50616288UL     // [NE] float4 exp-scores 12.8 MB
// end 63,416,288

__device__ __forceinline__ int clampi(int v, int hi) {  // [0, hi)
    v = v < 0 ? 0 : v;
    return v >= hi ? hi - 1 : v;
}

// Wave-replicated dtype sniff (see round-8 notes).
__device__ __forceinline__ int sniff_isbf(const unsigned* xe_raw) {
    int lane = threadIdx.x & 63;
    unsigned w = xe_raw[lane];
    unsigned ex = (w >> 7) & 0xFFu;
    bool hit = (ex >= 115u && ex <= 131u);
    return __popcll(__ballot(hit)) >= 32;
}

// block 0: flag + a_h/a_t convert. blocks 1..128: weight split. blocks 129+:
// zero sums + histH + histT (10000 u32).
__global__ __launch_bounds__(256) void k_init(const unsigned* __restrict__ xe_raw,
                                              const void* __restrict__ ah_in, const void* __restrict__ at_in,
                                              const void* __restrict__ wh, const void* __restrict__ wt,
                                              unsigned* __restrict__ flag, float* __restrict__ ah32,
                                              float* __restrict__ at32,
                                              __bf16* __restrict__ whh, __bf16* __restrict__ whl,
                                              __bf16* __restrict__ wth, __bf16* __restrict__ wtl,
                                              unsigned* __restrict__ zero1) {
    int isbf = sniff_isbf(xe_raw);
    int t = threadIdx.x;
    if (blockIdx.x == 0) {
        if (t == 0) flag[0] = (unsigned)isbf;
        ah32[t] = isbf ? __bfloat162float(((const __hip_bfloat16*)ah_in)[t]) : ((const float*)ah_in)[t];
        at32[t] = isbf ? __bfloat162float(((const __hip_bfloat16*)at_in)[t]) : ((const float*)at_in)[t];
    } else if (blockIdx.x <= 128) {
        int i = (blockIdx.x - 1) * 256 + t;   // [0, 32768)
        if (isbf) {
            whh[i] = ((const __bf16*)wh)[i]; whl[i] = (__bf16)0.f;
            wth[i] = ((const __bf16*)wt)[i]; wtl[i] = (__bf16)0.f;
        } else {
            float a = ((const float*)wh)[i];
            float b = ((const float*)wt)[i];
            __bf16 ah_ = (__bf16)a, bh_ = (__bf16)b;
            whh[i] = ah_; whl[i] = (__bf16)(a - (float)ah_);
            wth[i] = bh_; wtl[i] = (__bf16)(b - (float)bh_);
        }
    } else {
        int stride = (gridDim.x - 129) * 256;
        for (int i = (blockIdx.x - 129) * 256 + t; i < 10000; i += stride) zero1[i] = 0u;
    }
}

// LDS-staged GEMM: block tile 128x128, 4 waves x 32 rows (round-6 notes).
#define GM 128
#define WROW 40
__global__ __launch_bounds__(256, 2) void k_gemm(const void* __restrict__ xe,
                                                 const unsigned* __restrict__ flag,
                                                 const __bf16* __restrict__ whh, const __bf16* __restrict__ whl,
                                                 const __bf16* __restrict__ wth, const __bf16* __restrict__ wtl,
                                                 __hip_bfloat16* __restrict__ xh, __hip_bfloat16* __restrict__ xt) {
    const int isbf = (int)flag[0];
    __shared__ __bf16 sw[4][128 * WROW];
    int t = threadIdx.x;
    int lane = t & 63, wave = t >> 6;
    int quad = lane >> 4, l16 = lane & 15;
    int rowBase = blockIdx.x * GM + wave * 32;
    int r0 = rowBase + l16, r1 = r0 + 16;
    int ar0 = r0 < NN ? r0 : NN - 1;
    int ar1 = r1 < NN ? r1 : NN - 1;

    f32x4 accH0[8], accH1[8], accT0[8], accT1[8];
    for (int i = 0; i < 8; ++i) {
        accH0[i] = (f32x4){0.f,0.f,0.f,0.f}; accH1[i] = (f32x4){0.f,0.f,0.f,0.f};
        accT0[i] = (f32x4){0.f,0.f,0.f,0.f}; accT1[i] = (f32x4){0.f,0.f,0.f,0.f};
    }
    const int nparts = isbf ? 2 : 4;
    const __bf16* wsrc[4] = {whh, wth, whl, wtl};

    for (int ks = 0; ks < 8; ++ks) {
        int kb = ks * 32;
        __syncthreads();
        for (int part = 0; part < nparts; ++part) {
            const __bf16* wp = wsrc[part];
            for (int half = 0; half < 2; ++half) {
                int idx = half * 256 + t;
                int row = idx >> 2, ko = (idx & 3) * 8;
                uint4 v = *(const uint4*)(wp + (size_t)row * KEH + kb + ko);
                *(uint4*)(&sw[part][row * WROW + ko]) = v;
            }
        }
        __syncthreads();

        bf16x8 a0h, a0l, a1h, a1l;
        if (isbf) {
            a0h = *(const bf16x8*)((const __bf16*)xe + (size_t)ar0 * KEH + kb + quad * 8);
            a1h = *(const bf16x8*)((const __bf16*)xe + (size_t)ar1 * KEH + kb + quad * 8);
        } else {
            const float* p0 = (const float*)xe + (size_t)ar0 * KEH + kb + quad * 8;
            const float* p1 = (const float*)xe + (size_t)ar1 * KEH + kb + quad * 8;
            float4 u0 = *(const float4*)p0, u1 = *(const float4*)(p0 + 4);
            float4 w0 = *(const float4*)p1, w1 = *(const float4*)(p1 + 4);
            float v0[8] = {u0.x,u0.y,u0.z,u0.w,u1.x,u1.y,u1.z,u1.w};
            float v1[8] = {w0.x,w0.y,w0.z,w0.w,w1.x,w1.y,w1.z,w1.w};
            for (int j = 0; j < 8; ++j) {
                __bf16 h0 = (__bf16)v0[j], h1 = (__bf16)v1[j];
                a0h[j] = h0; a0l[j] = (__bf16)(v0[j] - (float)h0);
                a1h[j] = h1; a1l[j] = (__bf16)(v1[j] - (float)h1);
            }
        }
        for (int ct = 0; ct < 8; ++ct) {
            int fo = (ct * 16 + l16) * WROW + quad * 8;
            bf16x8 fh = *(const bf16x8*)(&sw[0][fo]);
            bf16x8 ft = *(const bf16x8*)(&sw[1][fo]);
            accH0[ct] = __builtin_amdgcn_mfma_f32_16x16x32_bf16(a0h, fh, accH0[ct], 0, 0, 0);
            accH1[ct] = __builtin_amdgcn_mfma_f32_16x16x32_bf16(a1h, fh, accH1[ct], 0, 0, 0);
            accT0[ct] = __builtin_amdgcn_mfma_f32_16x16x32_bf16(a0h, ft, accT0[ct], 0, 0, 0);
            accT1[ct] = __builtin_amdgcn_mfma_f32_16x16x32_bf16(a1h, ft, accT1[ct], 0, 0, 0);
            if (!isbf) {
                bf16x8 fhl = *(const bf16x8*)(&sw[2][fo]);
                bf16x8 ftl = *(const bf16x8*)(&sw[3][fo]);
                accH0[ct] = __builtin_amdgcn_mfma_f32_16x16x32_bf16(a0l, fh,  accH0[ct], 0, 0, 0);
                accH0[ct] = __builtin_amdgcn_mfma_f32_16x16x32_bf16(a0h, fhl, accH0[ct], 0, 0, 0);
                accH1[ct] = __builtin_amdgcn_mfma_f32_16x16x32_bf16(a1l, fh,  accH1[ct], 0, 0, 0);
                accH1[ct] = __builtin_amdgcn_mfma_f32_16x16x32_bf16(a1h, fhl, accH1[ct], 0, 0, 0);
                accT0[ct] = __builtin_amdgcn_mfma_f32_16x16x32_bf16(a0l, ft,  accT0[ct], 0, 0, 0);
                accT0[ct] = __builtin_amdgcn_mfma_f32_16x16x32_bf16(a0h, ftl, accT0[ct], 0, 0, 0);
                accT1[ct] = __builtin_amdgcn_mfma_f32_16x16x32_bf16(a1l, ft,  accT1[ct], 0, 0, 0);
                accT1[ct] = __builtin_amdgcn_mfma_f32_16x16x32_bf16(a1h, ftl, accT1[ct], 0, 0, 0);
            }
        }
    }
    for (int ct = 0; ct < 8; ++ct) {
        int col = ct * 16 + l16;
        for (int r2 = 0; r2 < 4; ++r2) {
            int o0 = rowBase + quad * 4 + r2;
            int o1 = o0 + 16;
            if (o0 < NN) {
                xh[(size_t)o0 * KRH + col] = __float2bfloat16(accH0[ct][r2]);
                xt[(size_t)o0 * KRH + col] = __float2bfloat16(accT0[ct][r2]);
            }
            if (o1 < NN) {
                xh[(size_t)o1 * KRH + col] = __float2bfloat16(accH1[ct][r2]);
                xt[(size_t)o1 * KRH + col] = __float2bfloat16(accT1[ct][r2]);
            }
        }
    }
}

// One wave per node: 8 dot products of length 128.
__global__ __launch_bounds__(256) void k_scores(const __hip_bfloat16* __restrict__ xh,
                                                const __hip_bfloat16* __restrict__ xt,
                                                const float* __restrict__ ah, const float* __restrict__ at,
                                                float4* __restrict__ sp, float4* __restrict__ dp) {
    int lane = threadIdx.x & 63;
    int w = threadIdx.x >> 6;
    int n = blockIdx.x * 4 + w;
    if (n >= NN) return;
    float xh0 = __bfloat162float(xh[(size_t)n*KRH + lane]);
    float xh1 = __bfloat162float(xh[(size_t)n*KRH + 64 + lane]);
    float xt0 = __bfloat162float(xt[(size_t)n*KRH + lane]);
    float xt1 = __bfloat162float(xt[(size_t)n*KRH + 64 + lane]);
    float ah00 = ah[lane],       ah01 = ah[64 + lane];
    float ah10 = ah[128 + lane], ah11 = ah[192 + lane];
    float at00 = at[lane],       at01 = at[64 + lane];
    float at10 = at[128 + lane], at11 = at[192 + lane];
    float v[8];
    v[0] = xh0*ah00 + xh1*ah01;
    v[1] = xh0*ah10 + xh1*ah11;
    v[2] = xt0*ah00 + xt1*ah01;
    v[3] = xt0*ah10 + xt1*ah11;
    v[4] = xt0*at00 + xt1*at01;
    v[5] = xt0*at10 + xt1*at11;
    v[6] = xh0*at00 + xh1*at01;
    v[7] = xh0*at10 + xh1*at11;
    for (int off = 32; off; off >>= 1)
        for (int j = 0; j < 8; ++j) v[j] += __shfl_xor(v[j], off);
    if (lane == 0) {
        sp[n] = make_float4(v[0], v[1], v[2], v[3]);
        dp[n] = make_float4(v[4], v[5], v[6], v[7]);
    }
}

__device__ __forceinline__ float eexp(float x) {
    x = x > 0.f ? x : 0.01f * x;
    x = fminf(x, 50.f);
    return __expf(x);
}

// Per edge (contiguous 3125-edge range per block, 1024 thr = 16 waves/CU):
// 4 exp scores -> ex4 store + LDS segment sums + (rel,sbin) histograms ->
// global totals (atomic) AND this block's private hpb row (non-atomic).
__global__ __launch_bounds__(1024) void k_edge(const int* __restrict__ src, const int* __restrict__ dst,
                                               const int* __restrict__ rel,
                                               const float4* __restrict__ sp, const float4* __restrict__ dp,
                                               float* __restrict__ sums,
                                               unsigned* __restrict__ histH, unsigned* __restrict__ histT,
                                               unsigned* __restrict__ hpbH, unsigned* __restrict__ hpbT,
                                               float4* __restrict__ ex4) {
    __shared__ float ls[NR * 4];
    __shared__ unsigned lhH[NBK], lhT[NBK];
    int t = threadIdx.x;
    for (int i = t; i < NR * 4; i += 1024) ls[i] = 0.f;
    for (int i = t; i < NBK; i += 1024) { lhH[i] = 0u; lhT[i] = 0u; }
    __syncthreads();
    unsigned lo = blockIdx.x * EPB, hi = lo + EPB;
    for (unsigned e = lo + t; e < hi; e += 1024) {
        int s = clampi(src[e], NN), d = clampi(dst[e], NN), r = clampi(rel[e], NR);
        float4 a = sp[s], b = dp[d];
        float4 ex;
        ex.x = eexp(a.x + b.x); ex.y = eexp(a.y + b.y);
        ex.z = eexp(a.z + b.z); ex.w = eexp(a.w + b.w);
        ex4[e] = ex;
        atomicAdd(&ls[r*4+0], ex.x);
        atomicAdd(&ls[r*4+1], ex.y);
        atomicAdd(&ls[r*4+2], ex.z);
        atomicAdd(&ls[r*4+3], ex.w);
        atomicAdd(&lhH[r * NSB + s / SBW], 1u);
        atomicAdd(&lhT[r * NSB + d / SBW], 1u);
    }
    __syncthreads();
    for (int i = t; i < NR * 4; i += 1024)
        if (ls[i] != 0.f) atomicAdd(&sums[i], ls[i]);
    size_t row = (size_t)blockIdx.x * NBK;
    for (int i = t; i < NBK; i += 1024) {
        unsigned cH = lhH[i], cT = lhT[i];
        hpbH[row + i] = cH;
        hpbT[row + i] = cT;
        if (cH) atomicAdd(&histH[i], cH);
        if (cT) atomicAdd(&histT[i], cT);
    }
}

// Scan both 4000-bin total histograms -> bucket bases; invs = 1/(sums+eps).
__global__ __launch_bounds__(1024) void k_scan2(const unsigned* __restrict__ histH,
                                                const unsigned* __restrict__ histT,
                                                const float* __restrict__ sums,
                                                unsigned* __restrict__ baseH, unsigned* __restrict__ baseT,
                                                float* __restrict__ invs) {
    __shared__ unsigned sc[1024];
    int t = threadIdx.x;
    for (int pass = 0; pass < 2; ++pass) {
        const unsigned* h = pass ? histT : histH;
        unsigned* base = pass ? baseT : baseH;
        int j0 = t * 4;
        unsigned v[4], s = 0;
        for (int k = 0; k < 4; ++k) { v[k] = (j0 + k < NBK) ? h[j0 + k] : 0u; s += v[k]; }
        sc[t] = s;
        __syncthreads();
        for (int off = 1; off < 1024; off <<= 1) {
            unsigned add = (t >= off) ? sc[t - off] : 0u;
            __syncthreads();
            sc[t] += add;
            __syncthreads();
        }
        unsigned run = sc[t] - s;
        for (int k = 0; k < 4; ++k) {
            if (j0 + k < NBK) { base[j0 + k] = run; run += v[k]; }
        }
        if (t == 1023) base[NBK] = sc[1023];
        __syncthreads();
    }
    for (int i = t; i < NR * 4; i += 1024) invs[i] = 1.f / (sums[i] + 1e-16f);
}

// Column scan: per (pass,bin), exclusive-scan the NBE per-block counts and add
// the bucket base -> hpb becomes each block's exact write offset. No atomics.
__global__ __launch_bounds__(NBE) void k_colscan(unsigned* __restrict__ hpbH, unsigned* __restrict__ hpbT,
                                                 const unsigned* __restrict__ baseH,
                                                 const unsigned* __restrict__ baseT) {
    __shared__ unsigned sc[NBE];
    int b = blockIdx.x;              // [0, 2*NBK)
    int pass = b >= NBK;
    int bin = pass ? b - NBK : b;
    unsigned* h = pass ? hpbT : hpbH;
    unsigned basev = (pass ? baseT : baseH)[bin];
    int t = threadIdx.x;
    unsigned v = h[(size_t)t * NBK + bin];
    sc[t] = v;
    __syncthreads();
    for (int off = 1; off < NBE; off <<= 1) {
        unsigned add = (t >= off) ? sc[t - off] : 0u;
        __syncthreads();
        sc[t] += add;
        __syncthreads();
    }
    h[(size_t)t * NBK + bin] = basev + sc[t] - v;
}

// Single-pass scatter (1024 thr): weights from streamed ex4 (no gathers, no
// exp); LDS cursors from precomputed per-block offsets.
__global__ __launch_bounds__(1024) void k_mkrec(const int* __restrict__ src, const int* __restrict__ dst,
                                                const int* __restrict__ rel,
                                                const float4* __restrict__ ex4,
                                                const float4* __restrict__ invs4,
                                                const unsigned* __restrict__ hpbH, const unsigned* __restrict__ hpbT,
                                                uint2* __restrict__ recH, uint2* __restrict__ recT) {
    __shared__ unsigned lcH[NBK], lcT[NBK];
    int t = threadIdx.x;
    size_t row = (size_t)blockIdx.x * NBK;
    for (int i = t; i < NBK; i += 1024) { lcH[i] = hpbH[row + i]; lcT[i] = hpbT[row + i]; }
    __syncthreads();
    unsigned lo = blockIdx.x * EPB, hi = lo + EPB;
    for (unsigned e = lo + t; e < hi; e += 1024) {
        int s = clampi(src[e], NN), d = clampi(dst[e], NN), r = clampi(rel[e], NR);
        float4 ex = ex4[e];
        float4 iv = invs4[r];
        float w1 = ex.x * iv.x + ex.y * iv.y;
        float w2 = ex.z * iv.z + ex.w * iv.w;
        unsigned pH = atomicAdd(&lcH[r * NSB + s / SBW], 1u);
        unsigned pT = atomicAdd(&lcT[r * NSB + d / SBW], 1u);
        if (pH < NE) recH[pH] = make_uint2((unsigned)s, __float_as_uint(w1));
        if (pT < NE) recT[pT] = make_uint2((unsigned)d, __float_as_uint(w2));
    }
}

// One block per (rel,sbin) bucket. Chunked: stage 256 recs into LDS in one
// coalesced burst, then each wave runs an 8-wide gather unroll with rec reads
// from LDS — rec-load latency off the critical path, 8 gathers in flight.
__global__ __launch_bounds__(256) void k_accR(const uint2* __restrict__ recH, const uint2* __restrict__ recT,
                                              const unsigned* __restrict__ baseH, const unsigned* __restrict__ baseT,
                                              const __hip_bfloat16* __restrict__ xh,
                                              const __hip_bfloat16* __restrict__ xt,
                                              float* __restrict__ part) {
    __shared__ float red[4][128];
    __shared__ uint2 lrec[256];
    int b = blockIdx.x;
    int t = threadIdx.x, lane = t & 63, wv = t >> 6;
    int c2 = lane * 2;
    float ax = 0.f, ay = 0.f;
    for (int pass = 0; pass < 2; ++pass) {
        const uint2* rec = pass ? recT : recH;
        const unsigned* base = pass ? baseT : baseH;
        const unsigned short* xs = (const unsigned short*)(pass ? xt : xh);
        unsigned b0 = base[b];
        unsigned cnt = base[b + 1] - b0;
        if (cnt > NE) cnt = 0;        // poison guard
        for (unsigned cb = 0; cb < cnt; cb += 256u) {
            unsigned cn = cnt - cb; if (cn > 256u) cn = 256u;
            __syncthreads();                       // prior chunk readers done
            if ((unsigned)t < cn) lrec[t] = rec[b0 + cb + t];
            __syncthreads();
            for (unsigned j = (unsigned)wv; j < cn; j += 32) {
                unsigned nd[8]; float w[8];
                #pragma unroll
                for (int k = 0; k < 8; ++k) {
                    unsigned jj = j + 4u * k;
                    bool m = jj < cn;
                    uint2 v = lrec[m ? jj : j];
                    nd[k] = v.x < NN ? v.x : 0u;
                    w[k] = m ? __uint_as_float(v.y) : 0.f;
                }
                unsigned u[8];
                #pragma unroll
                for (int k = 0; k < 8; ++k)
                    u[k] = *(const unsigned*)(xs + (size_t)nd[k] * KRH + c2);
                #pragma unroll
                for (int k = 0; k < 8; ++k) {
                    ax = fmaf(w[k], __uint_as_float(u[k] << 16), ax);
                    ay = fmaf(w[k], __uint_as_float(u[k] & 0xffff0000u), ay);
                }
            }
        }
    }
    __syncthreads();
    red[wv][c2] = ax; red[wv][c2 + 1] = ay;
    __syncthreads();
    if (wv == 0) {
        float vx = red[0][c2] + red[1][c2] + red[2][c2] + red[3][c2];
        float vy = red[0][c2+1] + red[1][c2+1] + red[2][c2+1] + red[3][c2+1];
        *(float2*)(&part[(size_t)b * KRH + c2]) = make_float2(vx, vy);
    }
}

// out[r][c] = 0.25 * sum_sbin part[r*8+sbin][c]; dtype follows input.
__global__ __launch_bounds__(256) void k_out(const float* __restrict__ part,
                                             const unsigned* __restrict__ flag, void* __restrict__ out) {
    int i = blockIdx.x * 256 + threadIdx.x;
    if (i < NR * KRH) {
        int r = i >> 7, c = i & 127;
        float v = 0.f;
        for (int s = 0; s < NSB; ++s) v += part[(size_t)(r * NSB + s) * KRH + c];
        v *= 0.25f;                   // / num_heads(2) / 2
        if (!isfinite(v)) v = 0.f;
        if (flag[0]) ((__hip_bfloat16*)out)[i] = __float2bfloat16(v);
        else         ((float*)out)[i] = v;
    }
}

extern "C" void kernel_launch(void* const* d_in, const int* in_sizes, int n_in,
                              void* d_out, int out_size, void* d_ws, size_t ws_size,
                              hipStream_t stream) {
    const void* xe  = d_in[0];
    const int* eidx = (const int*)d_in[1];
    const int* rel  = (const int*)d_in[2];
    const void* wh  = d_in[3];
    const void* wt  = d_in[4];
    const void* ahp = d_in[5];
    const void* atp = d_in[6];

    const int* src = eidx;
    const int* dst = eidx + NE;

    char* ws = (char*)d_ws;
    __hip_bfloat16* xh = (__hip_bfloat16*)(ws + OFF_XH);
    __hip_bfloat16* xt = (__hip_bfloat16*)(ws + OFF_XT);
    float4*   sp     = (float4*)(ws + OFF_SP);
    float4*   dp     = (float4*)(ws + OFF_DP);
    float*    sums   = (float*)(ws + OFF_SUMS);
    unsigned* histH  = (unsigned*)(ws + OFF_HISTH);
    unsigned* histT  = (unsigned*)(ws + OFF_HISTT);
    float*    invs   = (float*)(ws + OFF_INVS);
    unsigned* baseH  = (unsigned*)(ws + OFF_BASEH);
    unsigned* baseT  = (unsigned*)(ws + OFF_BASET);
    uint2*    recH   = (uint2*)(ws + OFF_RECH);
    uint2*    recT   = (uint2*)(ws + OFF_RECT);
    float*    partp  = (float*)(ws + OFF_PART);
    float*    ah32   = (float*)(ws + OFF_AH);
    float*    at32   = (float*)(ws + OFF_AT);
    unsigned* flag   = (unsigned*)(ws + OFF_FLAG);
    __bf16*   whh    = (__bf16*)(ws + OFF_WHH);
    __bf16*   whl    = (__bf16*)(ws + OFF_WHL);
    __bf16*   wth    = (__bf16*)(ws + OFF_WTH);
    __bf16*   wtl    = (__bf16*)(ws + OFF_WTL);
    unsigned* hpbH   = (unsigned*)(ws + OFF_HPBH);
    unsigned* hpbT   = (unsigned*)(ws + OFF_HPBT);
    float4*   ex4    = (float4*)(ws + OFF_EX);

    k_init<<<161, 256, 0, stream>>>((const unsigned*)xe, ahp, atp, wh, wt, flag, ah32, at32,
                                     whh, whl, wth, wtl, (unsigned*)(ws + OFF_SUMS));
    k_gemm<<<(NN + GM - 1) / GM, 256, 0, stream>>>(xe, flag, whh, whl, wth, wtl, xh, xt);
    k_scores<<<(NN + 3) / 4, 256, 0, stream>>>(xh, xt, ah32, at32, sp, dp);
    k_edge<<<NBE, 1024, 0, stream>>>(src, dst, rel, sp, dp, sums, histH, histT, hpbH, hpbT, ex4);
    k_scan2<<<1, 1024, 0, stream>>>(histH, histT, sums, baseH, baseT, invs);
    k_colscan<<<2 * NBK, NBE, 0, stream>>>(hpbH, hpbT, baseH, baseT);
    k_mkrec<<<NBE, 1024, 0, stream>>>(src, dst, rel, ex4, (const float4*)invs, hpbH, hpbT, recH, recT);
    k_accR<<<NBK, 256, 0, stream>>>(recH, recT, baseH, baseT, xh, xt, partp);
    k_out<<<(NR * KRH + 255) / 256, 256, 0, stream>>>(partp, flag, d_out);
}